// Round 2
// baseline (2156.154 us; speedup 1.0000x reference)
//
#include <hip/hip_runtime.h>

#define H  512
#define NN 10000
#define SS 20
#define VV 100000
#define EE 100000

typedef __bf16 bf16x8 __attribute__((ext_vector_type(8)));
typedef float  f32x4  __attribute__((ext_vector_type(4)));

__device__ __forceinline__ unsigned short f2bf(float f) {
  unsigned u = __builtin_bit_cast(unsigned, f);
  u += 0x7FFFu + ((u >> 16) & 1u);
  return (unsigned short)(u >> 16);
}
__device__ __forceinline__ float bflo(int x) {
  return __builtin_bit_cast(float, (unsigned)x << 16);
}
__device__ __forceinline__ float bfhi(int x) {
  return __builtin_bit_cast(float, (unsigned)x & 0xFFFF0000u);
}
__device__ __forceinline__ float sigm(float x) { return 1.f / (1.f + __expf(-x)); }

// pack two f32 -> two bf16 in one dword: round-half-up (+0x8000) + v_perm_b32.
__device__ __forceinline__ unsigned pk(float lo, float hi) {
  unsigned a = __builtin_bit_cast(unsigned, lo) + 0x8000u;
  unsigned b = __builtin_bit_cast(unsigned, hi) + 0x8000u;
  return __builtin_amdgcn_perm(b, a, 0x07060302u);
}
__device__ __forceinline__ void cvt_store8(unsigned short* dst, float4 a, float4 b) {
  int4 v;
  v.x = (int)pk(a.x, a.y); v.y = (int)pk(a.z, a.w);
  v.z = (int)pk(b.x, b.y); v.w = (int)pk(b.z, b.w);
  *(int4*)dst = v;
}
__device__ __forceinline__ bf16x8 cvt8(float4 a, float4 b) {
  int4 v;
  v.x = (int)pk(a.x, a.y); v.y = (int)pk(a.z, a.w);
  v.z = (int)pk(b.x, b.y); v.w = (int)pk(b.z, b.w);
  return __builtin_bit_cast(bf16x8, v);
}

// ---------------- fused gather + GEMM + GRU scan (persistent-B) -------------
// R1: occupancy 2 -> 4 waves/SIMD. Block = 512 thr = 8 waves covering 16
// channels. Wave = (colgroup cgl in 0..3, M-half mthalf in 0..1):
//   - 16-col B-tile per wave, packed col r = p(panel h/z) + 2*ly + 4*chl:
//     barr = 64 VGPR (was 128). acc = 3 f32x4 (was 10).
//   - M-half = time-step half of the scan (steps 0-11 / 12-19). Scan step is
//     affine h' = (1-z)h + z*yh, so each wave accumulates its range's affine
//     composite (aa,bb) lane-locally; h/z sit in adjacent lanes (shfl_xor(1)
//     per step); per-ng a tiny LDS compose joins 4 affines (2 mthalf x 2 ly):
//     hn = A1*B0 + B1 -- identical math to the old direct+affine compose.
// Staging/A-layout/swizzle identical to R0 (rows 0..79, XOR-swizzled
// granules, prefetch issued AFTER the barrier). 32 cgroups x 64 sb = 2048
// blocks; gathers duplicated 2x but L2-resident after the XCD swizzle:
//   hwid = by*32+bx, XCD = hwid&7; sb = (hwid&7)*8 + (hwid>>8),
//   cg = (hwid>>3)&31  (bijective; all 32 cg of an sb on one XCD).
__launch_bounds__(512, 4)
__global__ void gru_fused(const float* __restrict__ emb,
                          const float* __restrict__ W_ir,
                          const float* __restrict__ W_iz,
                          const float* __restrict__ b_ir,
                          const float* __restrict__ b_iz,
                          const int* __restrict__ walk,
                          unsigned short* __restrict__ hnb) {
  __shared__ unsigned short As[2][80 * 64];   // 2 x 10 KB, XOR-swizzled granules
  __shared__ float2 cmb[2][2][4][16];         // [mthalf][ly][node][ch] affines

  const int tid = threadIdx.x;
  const int w = tid >> 6, lane = tid & 63;
  const int r = lane & 15, q = lane >> 4;
  const int cgl = w & 3, mthalf = w >> 2;
  const int p = r & 1, ly = (r >> 1) & 1, chl = r >> 2;

  // XCD-aware remap (see header comment)
  const int hwid = blockIdx.y * 32 + blockIdx.x;
  const int cg = (hwid >> 3) & 31;
  const int sb = ((hwid & 7) << 3) + (hwid >> 8);
  const int c0 = cg * 16;

  // ---- persistent B fragments: 16 k-steps x 8 bf16 = 64 VGPRs --------------
  const int cch = c0 + cgl * 4 + chl;
  bf16x8 barr[16];
  float bias;
  {
    const float* wrow = (p ? W_iz : W_ir) + (long)ly * H * H + (long)cch * H;
    #pragma unroll
    for (int u = 0; u < 16; ++u) {
      const float* s = wrow + u * 32 + q * 8;
      barr[u] = cvt8(*(const float4*)s, *(const float4*)(s + 4));
    }
    bias = (p ? b_iz : b_ir)[ly * H + cch];
  }

  // ---- A staging roles: thread -> rows {tid>>3, 64+(tid>>3) if tid<128} ----
  const int row0 = tid >> 3, g0 = tid & 7;
  const bool has1 = (tid < 128);
  const int row1 = 64 + ((tid >> 3) & 15);
  #define LMAP(m) (20 * (((m) >> 2) & 3) + 4 * ((m) >> 4) + ((m) & 3))
  #define SWZ(m)  ((m) * 64 + ((g0 ^ ((m) & 7)) * 8))
  const int L0 = LMAP(row0), L1 = LMAP(row1);
  const int sw0 = SWZ(row0), sw1 = SWZ(row1);

  // ---- per-wave A-frag read bases (compile-time offsets off two bases) -----
  const int mtb = mthalf * 3;                 // first mt tile of this wave
  const int nmt = 3 - mthalf;                 // 3 tiles (steps 0-11) or 2 (12-19)
  const int abase = (mtb * 16 + r) * 64;
  const int sxo0 = ((q) ^ (r & 7)) * 8;       // ks=0 granule slot
  const int sxo1 = ((4 + q) ^ (r & 7)) * 8;   // ks=1 granule slot

  const int ngA = (2500 * sb) >> 6;
  const int ngB = (2500 * (sb + 1)) >> 6;

  int v0 = walk[ngA * 80 + L0]; v0 = ((unsigned)v0 < VV) ? v0 : 0;
  int cur0 = v0 * H, cur1 = 0;
  if (has1) { int v1 = walk[ngA * 80 + L1]; v1 = ((unsigned)v1 < VV) ? v1 : 0; cur1 = v1 * H; }

  float4 pa0, pb0, pa1 = {0,0,0,0}, pb1 = {0,0,0,0};
  {                                           // prologue: prefetch chunk 0
    const float* s0 = emb + cur0 + g0 * 8;
    pa0 = *(const float4*)s0; pb0 = *(const float4*)(s0 + 4);
    if (has1) { const float* s1 = emb + cur1 + g0 * 8;
                pa1 = *(const float4*)s1; pb1 = *(const float4*)(s1 + 4); }
  }

  f32x4 acc[3];
  const f32x4 fz = {0.f, 0.f, 0.f, 0.f};

  for (int ng = ngA; ng < ngB; ++ng) {
    #pragma unroll
    for (int j = 0; j < 3; ++j) acc[j] = fz;

    const int ngn = (ng + 1 < ngB) ? ng + 1 : ng;   // clamped walk prefetch
    int n0 = walk[ngn * 80 + L0]; n0 = ((unsigned)n0 < VV) ? n0 : 0;
    const int nxt0 = n0 * H;
    int nxt1 = 0;
    if (has1) { int n1 = walk[ngn * 80 + L1]; n1 = ((unsigned)n1 < VV) ? n1 : 0; nxt1 = n1 * H; }

    #pragma unroll
    for (int kc = 0; kc < 8; ++kc) {
      unsigned short* Ab = &As[kc & 1][0];
      // consume prefetched chunk kc -> LDS
      cvt_store8(&Ab[sw0], pa0, pb0);
      if (has1) cvt_store8(&Ab[sw1], pa1, pb1);
      __syncthreads();
      // prefetch chunk kc+1 (or next ng's chunk 0) AFTER the barrier:
      // nothing in flight at the drain; loads overlap the MFMA section.
      {
        const int ko = (kc < 7) ? (kc + 1) * 64 : 0;
        const int o0 = (kc < 7) ? cur0 : nxt0;
        const int o1 = (kc < 7) ? cur1 : nxt1;
        const float* s0 = emb + o0 + ko + g0 * 8;
        pa0 = *(const float4*)s0; pb0 = *(const float4*)(s0 + 4);
        if (has1) { const float* s1 = emb + o1 + ko + g0 * 8;
                    pa1 = *(const float4*)s1; pb1 = *(const float4*)(s1 + 4); }
      }
      // this wave's M-half MFMAs (wave-uniform bound; static acc indexing)
      #pragma unroll
      for (int ks = 0; ks < 2; ++ks) {
        const int sx = ks ? sxo1 : sxo0;
        #pragma unroll
        for (int j = 0; j < 3; ++j) {
          if (j < nmt) {
            bf16x8 a = *(const bf16x8*)&Ab[abase + j * 1024 + sx];
            acc[j] = __builtin_amdgcn_mfma_f32_16x16x32_bf16(
                a, barr[kc * 2 + ks], acc[j], 0, 0, 0);
          }
        }
      }
    }

    // ---- epilogue: per-wave affine composite over its step range -----------
    {
      float aa = 1.f, bb = 0.f;
      #pragma unroll
      for (int j = 0; j < 3; ++j) {
        if (j < nmt) {
          #pragma unroll
          for (int i = 0; i < 4; ++i) {
            const float y = acc[j][i] + bias;       // own biased preact
            const float t = __shfl_xor(y, 1);       // partner panel's preact
            const float yh = p ? t : y;
            const float yz = p ? y : t;
            const float z = sigm(yz);
            aa *= (1.f - z);
            bb += z * (yh - bb);
          }
        }
      }
      if (!p) cmb[mthalf][ly][q][cgl * 4 + chl] = make_float2(aa, bb);
    }
    __syncthreads();
    // compose 4 affines (2 mthalf x 2 ly) -> hn, store bf16 (coalesced 32B/node)
    if (tid < 64) {
      const int ch = tid & 15, nd = tid >> 4;
      const float2 c0a = cmb[0][0][nd][ch];   // ly0, steps 0-11
      const float2 c0b = cmb[1][0][nd][ch];   // ly0, steps 12-19
      const float2 c1a = cmb[0][1][nd][ch];   // ly1, steps 0-11
      const float2 c1b = cmb[1][1][nd][ch];   // ly1, steps 12-19
      const float B0 = c0b.x * c0a.y + c0b.y;             // h after layer 1
      const float hn = (c1b.x * c1a.x) * B0 + (c1b.x * c1a.y + c1b.y);
      hnb[(long)(ng * 4 + nd) * 1024 + c0 + ch] = f2bf(hn);
    }
    cur0 = nxt0; cur1 = nxt1;
  }
}

// ------- score slot (raw sigmoid) = sigmoid(hn . lin_w + lin_b) -------------
__global__ void score_kernel(const unsigned short* __restrict__ hnb,
                             const float* __restrict__ lin_w,
                             const float* __restrict__ lin_b,
                             float* __restrict__ R) {
  int tid = threadIdx.x;
  int wv = tid >> 6, lane = tid & 63;
  int node = blockIdx.x * 4 + wv;
  int k = lane * 8;
  int4 hv = *(const int4*)(hnb + (long)node * 1024 + k);
  float4 w0 = *(const float4*)(lin_w + k);
  float4 w1 = *(const float4*)(lin_w + k + 4);
  float s = bflo(hv.x) * w0.x + bfhi(hv.x) * w0.y + bflo(hv.y) * w0.z + bfhi(hv.y) * w0.w
          + bflo(hv.z) * w1.x + bfhi(hv.z) * w1.y + bflo(hv.w) * w1.z + bfhi(hv.w) * w1.w;
  #pragma unroll
  for (int off = 32; off > 0; off >>= 1) s += __shfl_down(s, off);
  if (lane == 0) R[256 + (long)node * 512] = sigm(s + lin_b[0]);
}

// ---------------- pred[e] = score[src] * score[dst] -------------------------
__global__ void pred_kernel(const int* __restrict__ eli, const float* __restrict__ R,
                            float* __restrict__ out) {
  int e = blockIdx.x * 256 + threadIdx.x;
  if (e < EE) {
    int a = eli[e];       a = (unsigned)a < NN ? a : 0;
    int b = eli[EE + e];  b = (unsigned)b < NN ? b : 0;
    out[e] = R[256 + (long)a * 512] * R[256 + (long)b * 512];
  }
}

// ---------------- out2 = hn @ skip_w.T + skip_b (in-place-safe MFMA) --------
__launch_bounds__(256)
__global__ void out2_kernel(const unsigned short* __restrict__ hnb,
                            const float* __restrict__ skip_w,
                            const float* __restrict__ skip_b,
                            float* __restrict__ out2) {
  __shared__ unsigned short Asl[32][520];
  __shared__ unsigned short Bsl[512][40];
  const int tid = threadIdx.x;
  const int lane = tid & 63, wv = tid >> 6;
  const int r = lane & 15, q = lane >> 4;
  const int m0 = blockIdx.x * 32;

  {
    int arow = tid >> 4;
    int acol = (tid & 15) * 32;
    #pragma unroll
    for (int hh = 0; hh < 2; ++hh) {
      int grow = m0 + hh * 16 + arow;
      unsigned short* dst = &Asl[hh * 16 + arow][acol];
      if (grow < NN) {
        const unsigned short* hr = hnb + (long)grow * 1024 + acol;
        *(int4*)(dst)      = *(const int4*)(hr);
        *(int4*)(dst + 8)  = *(const int4*)(hr + 8);
        *(int4*)(dst + 16) = *(const int4*)(hr + 16);
        *(int4*)(dst + 24) = *(const int4*)(hr + 24);
      } else {
        int4 z = {0, 0, 0, 0};
        *(int4*)(dst) = z; *(int4*)(dst + 8) = z;
        *(int4*)(dst + 16) = z; *(int4*)(dst + 24) = z;
      }
    }
  }

  const f32x4 fzero = {0.f, 0.f, 0.f, 0.f};
  f32x4 acc[2][8];
  #pragma unroll
  for (int rg = 0; rg < 2; ++rg)
    #pragma unroll
    for (int i = 0; i < 8; ++i) acc[rg][i] = fzero;

  const int ksub = (tid & 3) * 8;
  const int jb = tid >> 2;

  for (int k0 = 0; k0 < H; k0 += 32) {
    __syncthreads();
    #pragma unroll
    for (int it = 0; it < 8; ++it) {
      int jj = it * 64 + jb;
      const float* src = skip_w + (long)jj * H + k0 + ksub;
      cvt_store8(&Bsl[jj][ksub], *(const float4*)src, *(const float4*)(src + 4));
    }
    __syncthreads();
    bf16x8 af0 = *(const bf16x8*)&Asl[r][k0 + q * 8];
    bf16x8 af1 = *(const bf16x8*)&Asl[16 + r][k0 + q * 8];
    #pragma unroll
    for (int i = 0; i < 8; ++i) {
      bf16x8 bf = *(const bf16x8*)&Bsl[(wv * 8 + i) * 16 + r][q * 8];
      acc[0][i] = __builtin_amdgcn_mfma_f32_16x16x32_bf16(af0, bf, acc[0][i], 0, 0, 0);
      acc[1][i] = __builtin_amdgcn_mfma_f32_16x16x32_bf16(af1, bf, acc[1][i], 0, 0, 0);
    }
  }
  #pragma unroll
  for (int rg = 0; rg < 2; ++rg)
    #pragma unroll
    for (int i = 0; i < 8; ++i) {
      int col = (wv * 8 + i) * 16 + r;
      float sbv = skip_b[col];
      #pragma unroll
      for (int g = 0; g < 4; ++g) {
        int grow = m0 + rg * 16 + q * 4 + g;
        if (grow < NN) out2[(long)grow * H + col] = acc[rg][i][g] + sbv;
      }
    }
}

// ---------------- host launcher (d_ws is UNUSABLE in this harness) ----------
extern "C" void kernel_launch(void* const* d_in, const int* in_sizes, int n_in,
                              void* d_out, int out_size, void* d_ws, size_t ws_size,
                              hipStream_t stream) {
  const float* emb    = (const float*)d_in[0];
  const float* W_ir   = (const float*)d_in[1];
  const float* b_ir   = (const float*)d_in[2];
  const float* W_iz   = (const float*)d_in[3];
  const float* b_iz   = (const float*)d_in[4];
  const float* lin_w  = (const float*)d_in[5];
  const float* lin_b  = (const float*)d_in[6];
  const float* skip_w = (const float*)d_in[7];
  const float* skip_b = (const float*)d_in[8];
  const int*   walk   = (const int*)d_in[9];
  const int*   eli    = (const int*)d_in[10];
  float* out = (float*)d_out;
  float* R   = out + EE;                           // out2 region: NN x H f32
  unsigned short* hnb = (unsigned short*)R;        // bf16 hn inside out2 slots

  dim3 g1(32, 64);
  gru_fused<<<g1, 512, 0, stream>>>(emb, W_ir, W_iz, b_ir, b_iz, walk, hnb);
  score_kernel<<<2500, 256, 0, stream>>>(hnb, lin_w, lin_b, R);
  pred_kernel<<<391, 256, 0, stream>>>(eli, R, out);        // before out2 (slots reused)
  out2_kernel<<<313, 256, 0, stream>>>(hnb, skip_w, skip_b, R);
}

// Round 3
// 993.072 us; speedup vs baseline: 2.1712x; 2.1712x over previous
//
#include <hip/hip_runtime.h>

#define H  512
#define NN 10000
#define SS 20
#define VV 100000
#define EE 100000

typedef __bf16 bf16x8 __attribute__((ext_vector_type(8)));
typedef float  f32x4  __attribute__((ext_vector_type(4)));

__device__ __forceinline__ unsigned short f2bf(float f) {
  unsigned u = __builtin_bit_cast(unsigned, f);
  u += 0x7FFFu + ((u >> 16) & 1u);
  return (unsigned short)(u >> 16);
}
__device__ __forceinline__ float bflo(int x) {
  return __builtin_bit_cast(float, (unsigned)x << 16);
}
__device__ __forceinline__ float bfhi(int x) {
  return __builtin_bit_cast(float, (unsigned)x & 0xFFFF0000u);
}
__device__ __forceinline__ float sigm(float x) { return 1.f / (1.f + __expf(-x)); }

// pack two f32 -> two bf16 in one dword: round-half-up (+0x8000) + v_perm_b32.
__device__ __forceinline__ unsigned pk(float lo, float hi) {
  unsigned a = __builtin_bit_cast(unsigned, lo) + 0x8000u;
  unsigned b = __builtin_bit_cast(unsigned, hi) + 0x8000u;
  return __builtin_amdgcn_perm(b, a, 0x07060302u);
}
__device__ __forceinline__ void cvt_store8(unsigned short* dst, float4 a, float4 b) {
  int4 v;
  v.x = (int)pk(a.x, a.y); v.y = (int)pk(a.z, a.w);
  v.z = (int)pk(b.x, b.y); v.w = (int)pk(b.z, b.w);
  *(int4*)dst = v;
}
__device__ __forceinline__ bf16x8 cvt8(float4 a, float4 b) {
  int4 v;
  v.x = (int)pk(a.x, a.y); v.y = (int)pk(a.z, a.w);
  v.z = (int)pk(b.x, b.y); v.w = (int)pk(b.z, b.w);
  return __builtin_bit_cast(bf16x8, v);
}

// ---------------- fused gather + GEMM + GRU scan (persistent-B) -------------
// R2: occupancy via column-split, register-safe. Block = 256 thr = 4 waves,
// wave w = colgroup cgl in 0..3. Each wave owns 16 B-cols packed as
// col r = p(panel h/z) + 2*ly(layer) + 4*chl(channel 0..3):
//   barr = 64 VGPR (was 128 in the 783us kernel), acc = 5 f32x4, full M.
// R1 lesson: __launch_bounds__(512,4) capped regs at 128 < ~140 needed ->
// scratch spill (WRITE_SIZE 61->239MB, 3x dur). Here ~145 regs needed, cap
// (256,3) ~170 -> no spill, 3 blocks/CU = 3 waves/SIMD from 3 INDEPENDENT
// blocks (decorrelated barriers; R0's 2-wave config had both waves from
// blocks stalling on the same chain shape).
// Epilogue: both layers as affine composites per lane (verified in R1):
//   step: h' = (1-z)h + z*yh ; lane accumulates (aa,bb) over all 20 steps.
//   h/z sit in adjacent lanes: yh/yz via shfl_xor(1). Layer compose via
//   shfl_xor(2): hn = aa(ly1)*bb(ly0) + bb(ly1). No LDS, no per-ng barrier.
// Staging/A-layout/swizzle identical to R0 (80 rows, XOR-swizzled granules,
// prefetch issued AFTER the barrier; 0 bank conflicts verified).
// Grid 32 cgroups x 64 sb; XCD swizzle: hwid = by*32+bx, XCD = hwid&7;
// sb = (hwid&7)*8 + (hwid>>8), cg = (hwid>>3)&31 (bijective; all 32 cg of an
// sb on one XCD -> emb gathers L2-resident, verified R0: FETCH 1.33GB->246MB).
__launch_bounds__(256, 3)
__global__ void gru_fused(const float* __restrict__ emb,
                          const float* __restrict__ W_ir,
                          const float* __restrict__ W_iz,
                          const float* __restrict__ b_ir,
                          const float* __restrict__ b_iz,
                          const int* __restrict__ walk,
                          unsigned short* __restrict__ hnb) {
  __shared__ unsigned short As[2][80 * 64];   // 2 x 10 KB, XOR-swizzled granules

  const int tid = threadIdx.x;
  const int w = tid >> 6, lane = tid & 63;
  const int r = lane & 15, q = lane >> 4;
  const int cgl = w;                          // colgroup of this wave
  const int p = r & 1, ly = (r >> 1) & 1, chl = r >> 2;

  // XCD-aware remap (see header comment)
  const int hwid = blockIdx.y * 32 + blockIdx.x;
  const int cg = (hwid >> 3) & 31;
  const int sb = ((hwid & 7) << 3) + (hwid >> 8);
  const int c0 = cg * 16;

  // ---- persistent B fragments: 16 k-steps x 8 bf16 = 64 VGPRs --------------
  const int cch = c0 + cgl * 4 + chl;
  bf16x8 barr[16];
  float bias;
  {
    const float* wrow = (p ? W_iz : W_ir) + (long)ly * H * H + (long)cch * H;
    #pragma unroll
    for (int u = 0; u < 16; ++u) {
      const float* s = wrow + u * 32 + q * 8;
      barr[u] = cvt8(*(const float4*)s, *(const float4*)(s + 4));
    }
    bias = (p ? b_iz : b_ir)[ly * H + cch];
  }

  // ---- A staging roles: thread -> rows {tid>>3, +32, +64 (if tid<128)} -----
  const int row0 = tid >> 3, g0 = tid & 7;
  const int row1 = row0 + 32, row2 = row0 + 64;
  const bool has2 = (tid < 128);
  #define LMAP(m) (20 * (((m) >> 2) & 3) + 4 * ((m) >> 4) + ((m) & 3))
  #define SWZ(m)  ((m) * 64 + ((g0 ^ ((m) & 7)) * 8))
  const int L0 = LMAP(row0), L1 = LMAP(row1), L2 = LMAP(row2);
  const int sw0 = SWZ(row0), sw1 = SWZ(row1), sw2 = SWZ(row2);

  const int ngA = (2500 * sb) >> 6;
  const int ngB = (2500 * (sb + 1)) >> 6;

  int v0 = walk[ngA * 80 + L0]; v0 = ((unsigned)v0 < VV) ? v0 : 0;
  int v1 = walk[ngA * 80 + L1]; v1 = ((unsigned)v1 < VV) ? v1 : 0;
  int cur0 = v0 * H, cur1 = v1 * H, cur2 = 0;
  if (has2) { int v2 = walk[ngA * 80 + L2]; v2 = ((unsigned)v2 < VV) ? v2 : 0; cur2 = v2 * H; }

  float4 pa0, pb0, pa1, pb1, pa2 = {0,0,0,0}, pb2 = {0,0,0,0};
  {                                           // prologue: prefetch chunk 0
    const float* s0 = emb + cur0 + g0 * 8;
    pa0 = *(const float4*)s0; pb0 = *(const float4*)(s0 + 4);
    const float* s1 = emb + cur1 + g0 * 8;
    pa1 = *(const float4*)s1; pb1 = *(const float4*)(s1 + 4);
    if (has2) { const float* s2 = emb + cur2 + g0 * 8;
                pa2 = *(const float4*)s2; pb2 = *(const float4*)(s2 + 4); }
  }

  f32x4 acc[5];
  const f32x4 fz = {0.f, 0.f, 0.f, 0.f};

  for (int ng = ngA; ng < ngB; ++ng) {
    #pragma unroll
    for (int mt = 0; mt < 5; ++mt) acc[mt] = fz;

    const int ngn = (ng + 1 < ngB) ? ng + 1 : ng;   // clamped walk prefetch
    int n0 = walk[ngn * 80 + L0]; n0 = ((unsigned)n0 < VV) ? n0 : 0;
    int n1 = walk[ngn * 80 + L1]; n1 = ((unsigned)n1 < VV) ? n1 : 0;
    const int nxt0 = n0 * H, nxt1 = n1 * H;
    int nxt2 = 0;
    if (has2) { int n2 = walk[ngn * 80 + L2]; n2 = ((unsigned)n2 < VV) ? n2 : 0; nxt2 = n2 * H; }

    #pragma unroll
    for (int kc = 0; kc < 8; ++kc) {
      unsigned short* Ab = &As[kc & 1][0];
      // consume prefetched chunk kc -> LDS
      cvt_store8(&Ab[sw0], pa0, pb0);
      cvt_store8(&Ab[sw1], pa1, pb1);
      if (has2) cvt_store8(&Ab[sw2], pa2, pb2);
      __syncthreads();
      // prefetch chunk kc+1 (or next ng's chunk 0) AFTER the barrier:
      // nothing in flight at the drain; loads overlap the MFMA section.
      {
        const int ko = (kc < 7) ? (kc + 1) * 64 : 0;
        const int o0 = (kc < 7) ? cur0 : nxt0;
        const int o1 = (kc < 7) ? cur1 : nxt1;
        const int o2 = (kc < 7) ? cur2 : nxt2;
        const float* s0 = emb + o0 + ko + g0 * 8;
        pa0 = *(const float4*)s0; pb0 = *(const float4*)(s0 + 4);
        const float* s1 = emb + o1 + ko + g0 * 8;
        pa1 = *(const float4*)s1; pb1 = *(const float4*)(s1 + 4);
        if (has2) { const float* s2 = emb + o2 + ko + g0 * 8;
                    pa2 = *(const float4*)s2; pb2 = *(const float4*)(s2 + 4); }
      }
      #pragma unroll
      for (int ks = 0; ks < 2; ++ks) {
        bf16x8 a[5];
        #pragma unroll
        for (int mt = 0; mt < 5; ++mt) {
          const int ar = mt * 16 + r;
          a[mt] = *(const bf16x8*)&Ab[ar * 64 + (((ks * 4 + q) ^ (ar & 7)) * 8)];
        }
        #pragma unroll
        for (int mt = 0; mt < 5; ++mt)
          acc[mt] = __builtin_amdgcn_mfma_f32_16x16x32_bf16(
              a[mt], barr[kc * 2 + ks], acc[mt], 0, 0, 0);
      }
    }

    // ---- epilogue: both layers as lane-local affine composites -------------
    // lane holds 20 preacts for (node q, layer ly, channel cch, panel p).
    // shfl_xor(1) pairs h/z; both lanes of a pair compute identical (aa,bb).
    // Layer compose: hn = aa(ly1)*bb(ly0) + bb(ly1) via shfl_xor(2).
    {
      float aa = 1.f, bb = 0.f;
      #pragma unroll
      for (int s = 0; s < 20; ++s) {
        const float y = acc[s >> 2][s & 3] + bias;  // own biased preact
        const float t = __shfl_xor(y, 1);           // partner panel's preact
        const float yh = p ? t : y;
        const float yz = p ? y : t;
        const float z = sigm(yz);
        aa *= (1.f - z);
        bb += z * (yh - bb);
      }
      const float bbo = __shfl_xor(bb, 2);          // layer-1 h (= bb of ly0)
      if (ly == 1 && p == 0)
        hnb[(long)(ng * 4 + q) * 1024 + cch] = f2bf(aa * bbo + bb);
    }
    cur0 = nxt0; cur1 = nxt1; cur2 = nxt2;
  }
}

// ------- score slot (raw sigmoid) = sigmoid(hn . lin_w + lin_b) -------------
__global__ void score_kernel(const unsigned short* __restrict__ hnb,
                             const float* __restrict__ lin_w,
                             const float* __restrict__ lin_b,
                             float* __restrict__ R) {
  int tid = threadIdx.x;
  int wv = tid >> 6, lane = tid & 63;
  int node = blockIdx.x * 4 + wv;
  int k = lane * 8;
  int4 hv = *(const int4*)(hnb + (long)node * 1024 + k);
  float4 w0 = *(const float4*)(lin_w + k);
  float4 w1 = *(const float4*)(lin_w + k + 4);
  float s = bflo(hv.x) * w0.x + bfhi(hv.x) * w0.y + bflo(hv.y) * w0.z + bfhi(hv.y) * w0.w
          + bflo(hv.z) * w1.x + bfhi(hv.z) * w1.y + bflo(hv.w) * w1.z + bfhi(hv.w) * w1.w;
  #pragma unroll
  for (int off = 32; off > 0; off >>= 1) s += __shfl_down(s, off);
  if (lane == 0) R[256 + (long)node * 512] = sigm(s + lin_b[0]);
}

// ---------------- pred[e] = score[src] * score[dst] -------------------------
__global__ void pred_kernel(const int* __restrict__ eli, const float* __restrict__ R,
                            float* __restrict__ out) {
  int e = blockIdx.x * 256 + threadIdx.x;
  if (e < EE) {
    int a = eli[e];       a = (unsigned)a < NN ? a : 0;
    int b = eli[EE + e];  b = (unsigned)b < NN ? b : 0;
    out[e] = R[256 + (long)a * 512] * R[256 + (long)b * 512];
  }
}

// ---------------- out2 = hn @ skip_w.T + skip_b (in-place-safe MFMA) --------
__launch_bounds__(256)
__global__ void out2_kernel(const unsigned short* __restrict__ hnb,
                            const float* __restrict__ skip_w,
                            const float* __restrict__ skip_b,
                            float* __restrict__ out2) {
  __shared__ unsigned short Asl[32][520];
  __shared__ unsigned short Bsl[512][40];
  const int tid = threadIdx.x;
  const int lane = tid & 63, wv = tid >> 6;
  const int r = lane & 15, q = lane >> 4;
  const int m0 = blockIdx.x * 32;

  {
    int arow = tid >> 4;
    int acol = (tid & 15) * 32;
    #pragma unroll
    for (int hh = 0; hh < 2; ++hh) {
      int grow = m0 + hh * 16 + arow;
      unsigned short* dst = &Asl[hh * 16 + arow][acol];
      if (grow < NN) {
        const unsigned short* hr = hnb + (long)grow * 1024 + acol;
        *(int4*)(dst)      = *(const int4*)(hr);
        *(int4*)(dst + 8)  = *(const int4*)(hr + 8);
        *(int4*)(dst + 16) = *(const int4*)(hr + 16);
        *(int4*)(dst + 24) = *(const int4*)(hr + 24);
      } else {
        int4 z = {0, 0, 0, 0};
        *(int4*)(dst) = z; *(int4*)(dst + 8) = z;
        *(int4*)(dst + 16) = z; *(int4*)(dst + 24) = z;
      }
    }
  }

  const f32x4 fzero = {0.f, 0.f, 0.f, 0.f};
  f32x4 acc[2][8];
  #pragma unroll
  for (int rg = 0; rg < 2; ++rg)
    #pragma unroll
    for (int i = 0; i < 8; ++i) acc[rg][i] = fzero;

  const int ksub = (tid & 3) * 8;
  const int jb = tid >> 2;

  for (int k0 = 0; k0 < H; k0 += 32) {
    __syncthreads();
    #pragma unroll
    for (int it = 0; it < 8; ++it) {
      int jj = it * 64 + jb;
      const float* src = skip_w + (long)jj * H + k0 + ksub;
      cvt_store8(&Bsl[jj][ksub], *(const float4*)src, *(const float4*)(src + 4));
    }
    __syncthreads();
    bf16x8 af0 = *(const bf16x8*)&Asl[r][k0 + q * 8];
    bf16x8 af1 = *(const bf16x8*)&Asl[16 + r][k0 + q * 8];
    #pragma unroll
    for (int i = 0; i < 8; ++i) {
      bf16x8 bf = *(const bf16x8*)&Bsl[(wv * 8 + i) * 16 + r][q * 8];
      acc[0][i] = __builtin_amdgcn_mfma_f32_16x16x32_bf16(af0, bf, acc[0][i], 0, 0, 0);
      acc[1][i] = __builtin_amdgcn_mfma_f32_16x16x32_bf16(af1, bf, acc[1][i], 0, 0, 0);
    }
  }
  #pragma unroll
  for (int rg = 0; rg < 2; ++rg)
    #pragma unroll
    for (int i = 0; i < 8; ++i) {
      int col = (wv * 8 + i) * 16 + r;
      float sbv = skip_b[col];
      #pragma unroll
      for (int g = 0; g < 4; ++g) {
        int grow = m0 + rg * 16 + q * 4 + g;
        if (grow < NN) out2[(long)grow * H + col] = acc[rg][i][g] + sbv;
      }
    }
}

// ---------------- host launcher (d_ws is UNUSABLE in this harness) ----------
extern "C" void kernel_launch(void* const* d_in, const int* in_sizes, int n_in,
                              void* d_out, int out_size, void* d_ws, size_t ws_size,
                              hipStream_t stream) {
  const float* emb    = (const float*)d_in[0];
  const float* W_ir   = (const float*)d_in[1];
  const float* b_ir   = (const float*)d_in[2];
  const float* W_iz   = (const float*)d_in[3];
  const float* b_iz   = (const float*)d_in[4];
  const float* lin_w  = (const float*)d_in[5];
  const float* lin_b  = (const float*)d_in[6];
  const float* skip_w = (const float*)d_in[7];
  const float* skip_b = (const float*)d_in[8];
  const int*   walk   = (const int*)d_in[9];
  const int*   eli    = (const int*)d_in[10];
  float* out = (float*)d_out;
  float* R   = out + EE;                           // out2 region: NN x H f32
  unsigned short* hnb = (unsigned short*)R;        // bf16 hn inside out2 slots

  dim3 g1(32, 64);
  gru_fused<<<g1, 256, 0, stream>>>(emb, W_ir, W_iz, b_ir, b_iz, walk, hnb);
  score_kernel<<<2500, 256, 0, stream>>>(hnb, lin_w, lin_b, R);
  pred_kernel<<<391, 256, 0, stream>>>(eli, R, out);        // before out2 (slots reused)
  out2_kernel<<<313, 256, 0, stream>>>(hnb, skip_w, skip_b, R);
}

// Round 4
// 839.943 us; speedup vs baseline: 2.5670x; 1.1823x over previous
//
#include <hip/hip_runtime.h>

#define H  512
#define NN 10000
#define SS 20
#define VV 100000
#define EE 100000

typedef __bf16 bf16x8 __attribute__((ext_vector_type(8)));
typedef float  f32x4  __attribute__((ext_vector_type(4)));

__device__ __forceinline__ unsigned short f2bf(float f) {
  unsigned u = __builtin_bit_cast(unsigned, f);
  u += 0x7FFFu + ((u >> 16) & 1u);
  return (unsigned short)(u >> 16);
}
__device__ __forceinline__ float bflo(int x) {
  return __builtin_bit_cast(float, (unsigned)x << 16);
}
__device__ __forceinline__ float bfhi(int x) {
  return __builtin_bit_cast(float, (unsigned)x & 0xFFFF0000u);
}
__device__ __forceinline__ float sigm(float x) { return 1.f / (1.f + __expf(-x)); }

// pack two f32 -> two bf16 in one dword: round-half-up (+0x8000) + v_perm_b32.
__device__ __forceinline__ unsigned pk(float lo, float hi) {
  unsigned a = __builtin_bit_cast(unsigned, lo) + 0x8000u;
  unsigned b = __builtin_bit_cast(unsigned, hi) + 0x8000u;
  return __builtin_amdgcn_perm(b, a, 0x07060302u);
}
__device__ __forceinline__ void cvt_store8(unsigned short* dst, float4 a, float4 b) {
  int4 v;
  v.x = (int)pk(a.x, a.y); v.y = (int)pk(a.z, a.w);
  v.z = (int)pk(b.x, b.y); v.w = (int)pk(b.z, b.w);
  *(int4*)dst = v;
}
__device__ __forceinline__ bf16x8 cvt8(float4 a, float4 b) {
  int4 v;
  v.x = (int)pk(a.x, a.y); v.y = (int)pk(a.z, a.w);
  v.z = (int)pk(b.x, b.y); v.w = (int)pk(b.z, b.w);
  return __builtin_bit_cast(bf16x8, v);
}

// ---------------- fused gather + GEMM + GRU scan (persistent-B) -------------
// Geometry = the verified 731us config: grid (16 cgroups x 64 sb), 256 thr =
// 4 waves, wave owns 32 cols (h/z panels of same (layer,channel)), barr = 128
// VGPR persistent B, acc[5][2], BK=64, 80-row XOR-swizzled A (0 conflicts).
// R2 lesson: column-splitting duplicates staging (VALU+LDS) without cutting
// the wall -> reverted. R3 changes ONLY the kc-loop phase structure:
//   old: store(kc) -> barrier -> [loads(kc+1) ; reads+MFMA(kc)]   (phases SUM)
//   new: [reads(kc) ; issue loads(kc+1) ; MFMA(kc)] -> sched_barrier(0) ->
//        [vmcnt-wait ; cvt_store(kc+1) -> other buffer] -> barrier
// The staging VALU+ds_write now run after the MFMA burst in the same section
// (different pipes; loads get ~700cy to land vs L2-hit ~200cy), so the slot
// shrinks from sum(phases) ~2850cy toward max(MFMA 776, LDS 1120).
// sched_barrier(0) keeps the compiler from hoisting the store's vmcnt(0)
// above the MFMAs. Prefetch addresses are unrolled-kc immediate offsets
// (base + (kc+1)*256B) -> no per-kc address VALU.
// XCD swizzle (verified R0: FETCH 1.33GB -> 246MB): hwid = by*16+bx;
// sb = (hwid&7)*8 + (hwid>>7), cg = (hwid>>3)&15 -> all 16 cg of an sb on
// one XCD, emb gathers L2-resident.
__launch_bounds__(256, 2)
__global__ void gru_fused(const float* __restrict__ emb,
                          const float* __restrict__ W_ir,
                          const float* __restrict__ W_iz,
                          const float* __restrict__ b_ir,
                          const float* __restrict__ b_iz,
                          const int* __restrict__ walk,
                          unsigned short* __restrict__ hnb) {
  __shared__ unsigned short As[2][80 * 64];   // 2 x 10 KB, XOR-swizzled granules
  __shared__ unsigned short hout[2][4][32];   // [ng&1][node][channel-local]

  const int tid = threadIdx.x;
  const int w = tid >> 6, lane = tid & 63;
  const int r = lane & 15, q = lane >> 4;

  // XCD-aware remap (see header comment)
  const int hwid = blockIdx.y * 16 + blockIdx.x;
  const int cg = (hwid >> 3) & 15;
  const int sb = ((hwid & 7) << 3) + (hwid >> 7);
  const int c0 = cg * 32;

  // ---- persistent B fragments: 2 tiles x 16 k-steps x 8 bf16 = 128 VGPRs ---
  const int ly = r & 1;                       // layer of this lane's columns
  const int cch = c0 + 8 * w + (r >> 1);      // channel of this lane's columns
  bf16x8 barr[2][16];
  float bias2[2];
  #pragma unroll
  for (int t = 0; t < 2; ++t) {               // t: 0 = h (W_ir), 1 = z (W_iz)
    const float* wrow = (t ? W_iz : W_ir) + (long)ly * H * H + (long)cch * H;
    #pragma unroll
    for (int u = 0; u < 16; ++u) {
      const float* s = wrow + u * 32 + q * 8;
      barr[t][u] = cvt8(*(const float4*)s, *(const float4*)(s + 4));
    }
    bias2[t] = (t ? b_iz : b_ir)[ly * H + cch];
  }

  // ---- A staging roles: thread -> rows {tid>>3, +32, +64 (if tid<128)} -----
  const int row0 = tid >> 3, g0 = tid & 7;
  const int row1 = row0 + 32, row2 = row0 + 64;
  const bool has2 = (tid < 128);
  #define LMAP(m) (20 * (((m) >> 2) & 3) + 4 * ((m) >> 4) + ((m) & 3))
  #define SWZ(m)  ((m) * 64 + ((g0 ^ ((m) & 7)) * 8))
  const int L0 = LMAP(row0), L1 = LMAP(row1), L2 = LMAP(row2);
  const int sw0 = SWZ(row0), sw1 = SWZ(row1), sw2 = SWZ(row2);

  const int sb2 = sb;
  const int ngA = (2500 * sb2) >> 6;
  const int ngB = (2500 * (sb2 + 1)) >> 6;

  int v0 = walk[ngA * 80 + L0]; v0 = ((unsigned)v0 < VV) ? v0 : 0;
  int v1 = walk[ngA * 80 + L1]; v1 = ((unsigned)v1 < VV) ? v1 : 0;
  int cur0 = v0 * H, cur1 = v1 * H, cur2 = 0;
  if (has2) { int v2 = walk[ngA * 80 + L2]; v2 = ((unsigned)v2 < VV) ? v2 : 0; cur2 = v2 * H; }

  // ---- prologue: stage chunk 0 of the first ng into As[0] ------------------
  {
    const float* s0 = emb + cur0 + g0 * 8;
    float4 qa0 = *(const float4*)s0, qb0 = *(const float4*)(s0 + 4);
    const float* s1 = emb + cur1 + g0 * 8;
    float4 qa1 = *(const float4*)s1, qb1 = *(const float4*)(s1 + 4);
    float4 qa2 = {0,0,0,0}, qb2 = {0,0,0,0};
    if (has2) { const float* s2 = emb + cur2 + g0 * 8;
                qa2 = *(const float4*)s2; qb2 = *(const float4*)(s2 + 4); }
    cvt_store8(&As[0][sw0], qa0, qb0);
    cvt_store8(&As[0][sw1], qa1, qb1);
    if (has2) cvt_store8(&As[0][sw2], qa2, qb2);
  }
  __syncthreads();

  f32x4 acc[5][2];
  const f32x4 fz = {0.f, 0.f, 0.f, 0.f};

  for (int ng = ngA; ng < ngB; ++ng) {
    #pragma unroll
    for (int mt = 0; mt < 5; ++mt)
      #pragma unroll
      for (int t = 0; t < 2; ++t) acc[mt][t] = fz;

    const int ngn = (ng + 1 < ngB) ? ng + 1 : ng;   // clamped walk prefetch
    int n0 = walk[ngn * 80 + L0]; n0 = ((unsigned)n0 < VV) ? n0 : 0;
    int n1 = walk[ngn * 80 + L1]; n1 = ((unsigned)n1 < VV) ? n1 : 0;
    const int nxt0 = n0 * H, nxt1 = n1 * H;
    int nxt2 = 0;
    if (has2) { int n2 = walk[ngn * 80 + L2]; n2 = ((unsigned)n2 < VV) ? n2 : 0; nxt2 = n2 * H; }

    // per-ng load bases (immediate kc offsets fold into the load encoding)
    const float* b0c = emb + cur0 + g0 * 8;
    const float* b1c = emb + cur1 + g0 * 8;
    const float* b2c = emb + cur2 + g0 * 8;
    const float* b0n = emb + nxt0 + g0 * 8;
    const float* b1n = emb + nxt1 + g0 * 8;
    const float* b2n = emb + nxt2 + g0 * 8;

    #pragma unroll
    for (int kc = 0; kc < 8; ++kc) {
      unsigned short* Ab = &As[kc & 1][0];        // full (barrier'd last iter)
      unsigned short* An = &As[(kc + 1) & 1][0];  // target for next chunk

      // (2) issue prefetch loads for chunk kc+1 (next ng's chunk 0 at kc=7)
      const float* sA = (kc < 7) ? (b0c + (kc + 1) * 64) : b0n;
      const float* sB = (kc < 7) ? (b1c + (kc + 1) * 64) : b1n;
      float4 qa0 = *(const float4*)sA, qb0 = *(const float4*)(sA + 4);
      float4 qa1 = *(const float4*)sB, qb1 = *(const float4*)(sB + 4);
      float4 qa2 = {0,0,0,0}, qb2 = {0,0,0,0};
      if (has2) {
        const float* sC = (kc < 7) ? (b2c + (kc + 1) * 64) : b2n;
        qa2 = *(const float4*)sC; qb2 = *(const float4*)(sC + 4);
      }

      // (1)+(3) A-frag reads + MFMA burst (per-ks to keep live range small)
      #pragma unroll
      for (int ks = 0; ks < 2; ++ks) {
        bf16x8 a[5];
        #pragma unroll
        for (int mt = 0; mt < 5; ++mt) {
          const int ar = mt * 16 + r;
          a[mt] = *(const bf16x8*)&Ab[ar * 64 + (((ks * 4 + q) ^ (ar & 7)) * 8)];
        }
        #pragma unroll
        for (int mt = 0; mt < 5; ++mt)
          #pragma unroll
          for (int t = 0; t < 2; ++t)
            acc[mt][t] = __builtin_amdgcn_mfma_f32_16x16x32_bf16(
                a[mt], barr[t][kc * 2 + ks], acc[mt][t], 0, 0, 0);
      }

      // (4) keep the store (and its vmcnt wait) BELOW the MFMA burst
      __builtin_amdgcn_sched_barrier(0);
      cvt_store8(&An[sw0], qa0, qb0);
      cvt_store8(&An[sw1], qa1, qb1);
      if (has2) cvt_store8(&An[sw2], qa2, qb2);
      // (5) one barrier per kc: publishes chunk kc+1, retires reads of kc
      __syncthreads();
    }

    // ---- epilogue: pure lane-local scan (h and z live in the same lane) ----
    {
      float hn1 = 0.f, a2 = 1.f, b2 = 0.f;
      #pragma unroll
      for (int s = 0; s < 20; ++s) {
        const float yh = acc[s >> 2][0][s & 3] + bias2[0];
        const float yz = acc[s >> 2][1][s & 3] + bias2[1];
        const float z = sigm(yz);
        hn1 += z * (yh - hn1);     // layer-1 direct scan (valid on ly==0 lanes)
        a2 *= (1.f - z);           // layer-2 affine (valid on ly==1 lanes)
        b2 += z * (yh - b2);
      }
      const float u2 = __shfl_xor(hn1, 1);    // ly1 lane gets ly0's hn1
      if (ly == 1) hout[ng & 1][q][8 * w + (r >> 1)] = f2bf(a2 * u2 + b2);
    }
    __syncthreads();
    // packed store: 16 threads write 4 nodes x 64B (4 x dwordx4, same line)
    if (tid < 16) {
      const int nd = tid >> 2, seg = tid & 3;
      int4 v = *(const int4*)&hout[ng & 1][nd][seg * 8];
      *(int4*)(hnb + (long)(ng * 4 + nd) * 1024 + c0 + seg * 8) = v;
    }
    cur0 = nxt0; cur1 = nxt1; cur2 = nxt2;
  }
}

// ------- score slot (raw sigmoid) = sigmoid(hn . lin_w + lin_b) -------------
__global__ void score_kernel(const unsigned short* __restrict__ hnb,
                             const float* __restrict__ lin_w,
                             const float* __restrict__ lin_b,
                             float* __restrict__ R) {
  int tid = threadIdx.x;
  int wv = tid >> 6, lane = tid & 63;
  int node = blockIdx.x * 4 + wv;
  int k = lane * 8;
  int4 hv = *(const int4*)(hnb + (long)node * 1024 + k);
  float4 w0 = *(const float4*)(lin_w + k);
  float4 w1 = *(const float4*)(lin_w + k + 4);
  float s = bflo(hv.x) * w0.x + bfhi(hv.x) * w0.y + bflo(hv.y) * w0.z + bfhi(hv.y) * w0.w
          + bflo(hv.z) * w1.x + bfhi(hv.z) * w1.y + bflo(hv.w) * w1.z + bfhi(hv.w) * w1.w;
  #pragma unroll
  for (int off = 32; off > 0; off >>= 1) s += __shfl_down(s, off);
  if (lane == 0) R[256 + (long)node * 512] = sigm(s + lin_b[0]);
}

// ---------------- pred[e] = score[src] * score[dst] -------------------------
__global__ void pred_kernel(const int* __restrict__ eli, const float* __restrict__ R,
                            float* __restrict__ out) {
  int e = blockIdx.x * 256 + threadIdx.x;
  if (e < EE) {
    int a = eli[e];       a = (unsigned)a < NN ? a : 0;
    int b = eli[EE + e];  b = (unsigned)b < NN ? b : 0;
    out[e] = R[256 + (long)a * 512] * R[256 + (long)b * 512];
  }
}

// ---------------- out2 = hn @ skip_w.T + skip_b (in-place-safe MFMA) --------
__launch_bounds__(256)
__global__ void out2_kernel(const unsigned short* __restrict__ hnb,
                            const float* __restrict__ skip_w,
                            const float* __restrict__ skip_b,
                            float* __restrict__ out2) {
  __shared__ unsigned short Asl[32][520];
  __shared__ unsigned short Bsl[512][40];
  const int tid = threadIdx.x;
  const int lane = tid & 63, wv = tid >> 6;
  const int r = lane & 15, q = lane >> 4;
  const int m0 = blockIdx.x * 32;

  {
    int arow = tid >> 4;
    int acol = (tid & 15) * 32;
    #pragma unroll
    for (int hh = 0; hh < 2; ++hh) {
      int grow = m0 + hh * 16 + arow;
      unsigned short* dst = &Asl[hh * 16 + arow][acol];
      if (grow < NN) {
        const unsigned short* hr = hnb + (long)grow * 1024 + acol;
        *(int4*)(dst)      = *(const int4*)(hr);
        *(int4*)(dst + 8)  = *(const int4*)(hr + 8);
        *(int4*)(dst + 16) = *(const int4*)(hr + 16);
        *(int4*)(dst + 24) = *(const int4*)(hr + 24);
      } else {
        int4 z = {0, 0, 0, 0};
        *(int4*)(dst) = z; *(int4*)(dst + 8) = z;
        *(int4*)(dst + 16) = z; *(int4*)(dst + 24) = z;
      }
    }
  }

  const f32x4 fzero = {0.f, 0.f, 0.f, 0.f};
  f32x4 acc[2][8];
  #pragma unroll
  for (int rg = 0; rg < 2; ++rg)
    #pragma unroll
    for (int i = 0; i < 8; ++i) acc[rg][i] = fzero;

  const int ksub = (tid & 3) * 8;
  const int jb = tid >> 2;

  for (int k0 = 0; k0 < H; k0 += 32) {
    __syncthreads();
    #pragma unroll
    for (int it = 0; it < 8; ++it) {
      int jj = it * 64 + jb;
      const float* src = skip_w + (long)jj * H + k0 + ksub;
      cvt_store8(&Bsl[jj][ksub], *(const float4*)src, *(const float4*)(src + 4));
    }
    __syncthreads();
    bf16x8 af0 = *(const bf16x8*)&Asl[r][k0 + q * 8];
    bf16x8 af1 = *(const bf16x8*)&Asl[16 + r][k0 + q * 8];
    #pragma unroll
    for (int i = 0; i < 8; ++i) {
      bf16x8 bf = *(const bf16x8*)&Bsl[(wv * 8 + i) * 16 + r][q * 8];
      acc[0][i] = __builtin_amdgcn_mfma_f32_16x16x32_bf16(af0, bf, acc[0][i], 0, 0, 0);
      acc[1][i] = __builtin_amdgcn_mfma_f32_16x16x32_bf16(af1, bf, acc[1][i], 0, 0, 0);
    }
  }
  #pragma unroll
  for (int rg = 0; rg < 2; ++rg)
    #pragma unroll
    for (int i = 0; i < 8; ++i) {
      int col = (wv * 8 + i) * 16 + r;
      float sbv = skip_b[col];
      #pragma unroll
      for (int g = 0; g < 4; ++g) {
        int grow = m0 + rg * 16 + q * 4 + g;
        if (grow < NN) out2[(long)grow * H + col] = acc[rg][i][g] + sbv;
      }
    }
}

// ---------------- host launcher (d_ws is UNUSABLE in this harness) ----------
extern "C" void kernel_launch(void* const* d_in, const int* in_sizes, int n_in,
                              void* d_out, int out_size, void* d_ws, size_t ws_size,
                              hipStream_t stream) {
  const float* emb    = (const float*)d_in[0];
  const float* W_ir   = (const float*)d_in[1];
  const float* b_ir   = (const float*)d_in[2];
  const float* W_iz   = (const float*)d_in[3];
  const float* b_iz   = (const float*)d_in[4];
  const float* lin_w  = (const float*)d_in[5];
  const float* lin_b  = (const float*)d_in[6];
  const float* skip_w = (const float*)d_in[7];
  const float* skip_b = (const float*)d_in[8];
  const int*   walk   = (const int*)d_in[9];
  const int*   eli    = (const int*)d_in[10];
  float* out = (float*)d_out;
  float* R   = out + EE;                           // out2 region: NN x H f32
  unsigned short* hnb = (unsigned short*)R;        // bf16 hn inside out2 slots

  dim3 g1(16, 64);
  gru_fused<<<g1, 256, 0, stream>>>(emb, W_ir, W_iz, b_ir, b_iz, walk, hnb);
  score_kernel<<<2500, 256, 0, stream>>>(hnb, lin_w, lin_b, R);
  pred_kernel<<<391, 256, 0, stream>>>(eli, R, out);        // before out2 (slots reused)
  out2_kernel<<<313, 256, 0, stream>>>(hnb, skip_w, skip_b, R);
}

// Round 5
// 743.549 us; speedup vs baseline: 2.8998x; 1.1296x over previous
//
#include <hip/hip_runtime.h>

#define H  512
#define NN 10000
#define SS 20
#define VV 100000
#define EE 100000

typedef __bf16 bf16x8 __attribute__((ext_vector_type(8)));
typedef float  f32x4  __attribute__((ext_vector_type(4)));

__device__ __forceinline__ unsigned short f2bf(float f) {
  unsigned u = __builtin_bit_cast(unsigned, f);
  u += 0x7FFFu + ((u >> 16) & 1u);
  return (unsigned short)(u >> 16);
}
__device__ __forceinline__ float bflo(int x) {
  return __builtin_bit_cast(float, (unsigned)x << 16);
}
__device__ __forceinline__ float bfhi(int x) {
  return __builtin_bit_cast(float, (unsigned)x & 0xFFFF0000u);
}
__device__ __forceinline__ float sigm(float x) { return 1.f / (1.f + __expf(-x)); }

// pack two f32 -> two bf16 in one dword: round-half-up (+0x8000) + v_perm_b32.
__device__ __forceinline__ unsigned pk(float lo, float hi) {
  unsigned a = __builtin_bit_cast(unsigned, lo) + 0x8000u;
  unsigned b = __builtin_bit_cast(unsigned, hi) + 0x8000u;
  return __builtin_amdgcn_perm(b, a, 0x07060302u);
}
__device__ __forceinline__ void cvt_store8(unsigned short* dst, float4 a, float4 b) {
  int4 v;
  v.x = (int)pk(a.x, a.y); v.y = (int)pk(a.z, a.w);
  v.z = (int)pk(b.x, b.y); v.w = (int)pk(b.z, b.w);
  *(int4*)dst = v;
}
__device__ __forceinline__ bf16x8 cvt8(float4 a, float4 b) {
  int4 v;
  v.x = (int)pk(a.x, a.y); v.y = (int)pk(a.z, a.w);
  v.z = (int)pk(b.x, b.y); v.w = (int)pk(b.z, b.w);
  return __builtin_bit_cast(bf16x8, v);
}

// non-draining barrier: publish LDS writes, do NOT drain vmcnt (in-flight
// global loads legally span the barrier). "memory" clobber = compiler fence
// so ds ops can't be moved across it.
__device__ __forceinline__ void pub_barrier() {
  asm volatile("s_waitcnt lgkmcnt(0)\n\ts_barrier" ::: "memory");
}

// ---------------- fused gather + GEMM + GRU scan (persistent-B) -------------
// Geometry = verified 731us config: grid (16 cg x 64 sb), 256 thr = 4 waves,
// wave owns 32 cols (h/z panels of same (layer,channel)), barr = 128 VGPR
// persistent B, acc[5][2], BK=64, 80-row XOR-swizzled A (0 conflicts).
// R3 lesson: per-slot pipes SUM (VALU 486 + LDS 600 + MFMA 320 ~= slot 1390):
// store(kc)->barrier->read(kc)->MFMA(kc) serializes everything. R4 breaks the
// chain: 4 LDS buffers, ONE non-draining barrier per slot, store shifted two
// chunks ahead of its reader:
//   slot kc: [lgkm0; s_barrier] ; issue loads(kc+3) ; cvt_store(kc+2) ;
//            ds_read(kc) ; MFMA(kc)
// Store/cvt/load-issue share the scheduling region with read-latency + MFMA
// (different pipes -> compiler interleaves). Each buffer: write -> 2 barriers
// -> read -> 2 barriers -> rewrite (race-safe). vmcnt waits are compiler-auto
// (reg-staged loads; counts exact). ~250 VGPR total incl. acc -- fits 256.
// XCD swizzle (verified: FETCH 1.33GB->246MB): hwid = by*16+bx;
// sb = (hwid&7)*8 + (hwid>>7), cg = (hwid>>3)&15.
__launch_bounds__(256, 2)
__global__ void gru_fused(const float* __restrict__ emb,
                          const float* __restrict__ W_ir,
                          const float* __restrict__ W_iz,
                          const float* __restrict__ b_ir,
                          const float* __restrict__ b_iz,
                          const int* __restrict__ walk,
                          unsigned short* __restrict__ hnb) {
  __shared__ unsigned short As[4][80 * 64];   // 4 x 10 KB, XOR-swizzled granules
  __shared__ unsigned short hout[2][4][32];   // [ng&1][node][channel-local]

  const int tid = threadIdx.x;
  const int w = tid >> 6, lane = tid & 63;
  const int r = lane & 15, q = lane >> 4;

  // XCD-aware remap (see header comment)
  const int hwid = blockIdx.y * 16 + blockIdx.x;
  const int cg = (hwid >> 3) & 15;
  const int sb = ((hwid & 7) << 3) + (hwid >> 7);
  const int c0 = cg * 32;

  // ---- persistent B fragments: 2 tiles x 16 k-steps x 8 bf16 = 128 VGPRs ---
  const int ly = r & 1;                       // layer of this lane's columns
  const int cch = c0 + 8 * w + (r >> 1);      // channel of this lane's columns
  bf16x8 barr[2][16];
  float bias2[2];
  #pragma unroll
  for (int t = 0; t < 2; ++t) {               // t: 0 = h (W_ir), 1 = z (W_iz)
    const float* wrow = (t ? W_iz : W_ir) + (long)ly * H * H + (long)cch * H;
    #pragma unroll
    for (int u = 0; u < 16; ++u) {
      const float* s = wrow + u * 32 + q * 8;
      barr[t][u] = cvt8(*(const float4*)s, *(const float4*)(s + 4));
    }
    bias2[t] = (t ? b_iz : b_ir)[ly * H + cch];
  }

  // ---- A staging roles: thread -> rows {tid>>3, +32, +64 (if tid<128)} -----
  const int row0 = tid >> 3, g0 = tid & 7;
  const int row1 = row0 + 32, row2 = row0 + 64;
  const bool has2 = (tid < 128);              // wave-uniform (waves 0,1)
  #define LMAP(m) (20 * (((m) >> 2) & 3) + 4 * ((m) >> 4) + ((m) & 3))
  #define SWZ(m)  ((m) * 64 + ((g0 ^ ((m) & 7)) * 8))
  const int L0 = LMAP(row0), L1 = LMAP(row1), L2 = LMAP(row2);
  const int sw0 = SWZ(row0), sw1 = SWZ(row1), sw2 = SWZ(row2);

  const int ngA = (2500 * sb) >> 6;
  const int ngB = (2500 * (sb + 1)) >> 6;

  int v0 = walk[ngA * 80 + L0]; v0 = ((unsigned)v0 < VV) ? v0 : 0;
  int v1 = walk[ngA * 80 + L1]; v1 = ((unsigned)v1 < VV) ? v1 : 0;
  int cur0 = v0 * H, cur1 = v1 * H, cur2 = 0;
  if (has2) { int v2 = walk[ngA * 80 + L2]; v2 = ((unsigned)v2 < VV) ? v2 : 0; cur2 = v2 * H; }

  // pf regs: per row {a,b} float4, 2 parity slots (compile-time indexed)
  float4 p0a[2], p0b[2], p1a[2], p1b[2], p2a[2], p2b[2];
  p2a[0] = p2a[1] = p2b[0] = p2b[1] = (float4){0, 0, 0, 0};

  // ---- prologue: load+store chunks 0,1; issue loads for chunk 2 ------------
  {
    const float* s0 = emb + cur0 + g0 * 8;
    const float* s1 = emb + cur1 + g0 * 8;
    const float* s2 = emb + cur2 + g0 * 8;
    // chunk 0
    float4 a0 = *(const float4*)s0, b0 = *(const float4*)(s0 + 4);
    float4 a1 = *(const float4*)s1, b1 = *(const float4*)(s1 + 4);
    float4 a2 = {0,0,0,0}, b2 = {0,0,0,0};
    if (has2) { a2 = *(const float4*)s2; b2 = *(const float4*)(s2 + 4); }
    cvt_store8(&As[0][sw0], a0, b0);
    cvt_store8(&As[0][sw1], a1, b1);
    if (has2) cvt_store8(&As[0][sw2], a2, b2);
    // chunk 1
    a0 = *(const float4*)(s0 + 64); b0 = *(const float4*)(s0 + 68);
    a1 = *(const float4*)(s1 + 64); b1 = *(const float4*)(s1 + 68);
    if (has2) { a2 = *(const float4*)(s2 + 64); b2 = *(const float4*)(s2 + 68); }
    cvt_store8(&As[1][sw0], a0, b0);
    cvt_store8(&As[1][sw1], a1, b1);
    if (has2) cvt_store8(&As[1][sw2], a2, b2);
    // issue chunk 2 -> parity (2&1)=0
    p0a[0] = *(const float4*)(s0 + 128); p0b[0] = *(const float4*)(s0 + 132);
    p1a[0] = *(const float4*)(s1 + 128); p1b[0] = *(const float4*)(s1 + 132);
    if (has2) { p2a[0] = *(const float4*)(s2 + 128); p2b[0] = *(const float4*)(s2 + 132); }
  }

  f32x4 acc[5][2];
  const f32x4 fz = {0.f, 0.f, 0.f, 0.f};

  for (int ng = ngA; ng < ngB; ++ng) {
    #pragma unroll
    for (int mt = 0; mt < 5; ++mt)
      #pragma unroll
      for (int t = 0; t < 2; ++t) acc[mt][t] = fz;

    const int ngn = (ng + 1 < ngB) ? ng + 1 : ng;   // clamped walk prefetch
    int n0 = walk[ngn * 80 + L0]; n0 = ((unsigned)n0 < VV) ? n0 : 0;
    int n1 = walk[ngn * 80 + L1]; n1 = ((unsigned)n1 < VV) ? n1 : 0;
    const int nxt0 = n0 * H, nxt1 = n1 * H;
    int nxt2 = 0;
    if (has2) { int n2 = walk[ngn * 80 + L2]; n2 = ((unsigned)n2 < VV) ? n2 : 0; nxt2 = n2 * H; }

    #pragma unroll
    for (int kc = 0; kc < 8; ++kc) {
      // (a) publish previous slot's store; retire previous reads; no vm drain
      pub_barrier();

      // (b) issue loads for chunk kc+3 (wraps into next ng's chunks 0..2)
      {
        const int cix = kc + 3;                     // 3..10, compile-time
        const int off = (cix & 7) * 64;
        const int u0 = (cix < 8) ? cur0 : nxt0;
        const int u1 = (cix < 8) ? cur1 : nxt1;
        const float* s0 = emb + u0 + off + g0 * 8;
        p0a[cix & 1] = *(const float4*)s0; p0b[cix & 1] = *(const float4*)(s0 + 4);
        const float* s1 = emb + u1 + off + g0 * 8;
        p1a[cix & 1] = *(const float4*)s1; p1b[cix & 1] = *(const float4*)(s1 + 4);
        if (has2) {
          const int u2 = (cix < 8) ? cur2 : nxt2;
          const float* s2 = emb + u2 + off + g0 * 8;
          p2a[cix & 1] = *(const float4*)s2; p2b[cix & 1] = *(const float4*)(s2 + 4);
        }
      }

      // (c) cvt+store chunk kc+2 (loads issued last slot; compiler auto-vmcnt)
      {
        unsigned short* An = &As[(kc + 2) & 3][0];
        cvt_store8(&An[sw0], p0a[kc & 1], p0b[kc & 1]);   // (kc+2)&1 == kc&1
        cvt_store8(&An[sw1], p1a[kc & 1], p1b[kc & 1]);
        if (has2) cvt_store8(&An[sw2], p2a[kc & 1], p2b[kc & 1]);
      }

      // (d)+(e) frag reads + MFMA for chunk kc (published 1-2 barriers ago)
      const unsigned short* Ab = &As[kc & 3][0];
      #pragma unroll
      for (int ks = 0; ks < 2; ++ks) {
        bf16x8 a[5];
        #pragma unroll
        for (int mt = 0; mt < 5; ++mt) {
          const int ar = mt * 16 + r;
          a[mt] = *(const bf16x8*)&Ab[ar * 64 + (((ks * 4 + q) ^ (ar & 7)) * 8)];
        }
        __builtin_amdgcn_s_setprio(1);
        #pragma unroll
        for (int mt = 0; mt < 5; ++mt)
          #pragma unroll
          for (int t = 0; t < 2; ++t)
            acc[mt][t] = __builtin_amdgcn_mfma_f32_16x16x32_bf16(
                a[mt], barr[t][kc * 2 + ks], acc[mt][t], 0, 0, 0);
        __builtin_amdgcn_s_setprio(0);
      }
    }

    // ---- epilogue: pure lane-local scan (h and z live in the same lane) ----
    {
      float hn1 = 0.f, a2 = 1.f, b2 = 0.f;
      #pragma unroll
      for (int s = 0; s < 20; ++s) {
        const float yh = acc[s >> 2][0][s & 3] + bias2[0];
        const float yz = acc[s >> 2][1][s & 3] + bias2[1];
        const float z = sigm(yz);
        hn1 += z * (yh - hn1);     // layer-1 direct scan (valid on ly==0 lanes)
        a2 *= (1.f - z);           // layer-2 affine (valid on ly==1 lanes)
        b2 += z * (yh - b2);
      }
      const float u2 = __shfl_xor(hn1, 1);    // ly1 lane gets ly0's hn1
      if (ly == 1) hout[ng & 1][q][8 * w + (r >> 1)] = f2bf(a2 * u2 + b2);
    }
    pub_barrier();
    // packed store: 16 threads write 4 nodes x 64B (4 x dwordx4, same line)
    if (tid < 16) {
      const int nd = tid >> 2, seg = tid & 3;
      int4 v = *(const int4*)&hout[ng & 1][nd][seg * 8];
      *(int4*)(hnb + (long)(ng * 4 + nd) * 1024 + c0 + seg * 8) = v;
    }
    cur0 = nxt0; cur1 = nxt1; cur2 = nxt2;
  }
}

// ------- score slot (raw sigmoid) = sigmoid(hn . lin_w + lin_b) -------------
__global__ void score_kernel(const unsigned short* __restrict__ hnb,
                             const float* __restrict__ lin_w,
                             const float* __restrict__ lin_b,
                             float* __restrict__ R) {
  int tid = threadIdx.x;
  int wv = tid >> 6, lane = tid & 63;
  int node = blockIdx.x * 4 + wv;
  int k = lane * 8;
  int4 hv = *(const int4*)(hnb + (long)node * 1024 + k);
  float4 w0 = *(const float4*)(lin_w + k);
  float4 w1 = *(const float4*)(lin_w + k + 4);
  float s = bflo(hv.x) * w0.x + bfhi(hv.x) * w0.y + bflo(hv.y) * w0.z + bfhi(hv.y) * w0.w
          + bflo(hv.z) * w1.x + bfhi(hv.z) * w1.y + bflo(hv.w) * w1.z + bfhi(hv.w) * w1.w;
  #pragma unroll
  for (int off = 32; off > 0; off >>= 1) s += __shfl_down(s, off);
  if (lane == 0) R[256 + (long)node * 512] = sigm(s + lin_b[0]);
}

// ---------------- pred[e] = score[src] * score[dst] -------------------------
__global__ void pred_kernel(const int* __restrict__ eli, const float* __restrict__ R,
                            float* __restrict__ out) {
  int e = blockIdx.x * 256 + threadIdx.x;
  if (e < EE) {
    int a = eli[e];       a = (unsigned)a < NN ? a : 0;
    int b = eli[EE + e];  b = (unsigned)b < NN ? b : 0;
    out[e] = R[256 + (long)a * 512] * R[256 + (long)b * 512];
  }
}

// ---------------- out2 = hn @ skip_w.T + skip_b (in-place-safe MFMA) --------
__launch_bounds__(256)
__global__ void out2_kernel(const unsigned short* __restrict__ hnb,
                            const float* __restrict__ skip_w,
                            const float* __restrict__ skip_b,
                            float* __restrict__ out2) {
  __shared__ unsigned short Asl[32][520];
  __shared__ unsigned short Bsl[512][40];
  const int tid = threadIdx.x;
  const int lane = tid & 63, wv = tid >> 6;
  const int r = lane & 15, q = lane >> 4;
  const int m0 = blockIdx.x * 32;

  {
    int arow = tid >> 4;
    int acol = (tid & 15) * 32;
    #pragma unroll
    for (int hh = 0; hh < 2; ++hh) {
      int grow = m0 + hh * 16 + arow;
      unsigned short* dst = &Asl[hh * 16 + arow][acol];
      if (grow < NN) {
        const unsigned short* hr = hnb + (long)grow * 1024 + acol;
        *(int4*)(dst)      = *(const int4*)(hr);
        *(int4*)(dst + 8)  = *(const int4*)(hr + 8);
        *(int4*)(dst + 16) = *(const int4*)(hr + 16);
        *(int4*)(dst + 24) = *(const int4*)(hr + 24);
      } else {
        int4 z = {0, 0, 0, 0};
        *(int4*)(dst) = z; *(int4*)(dst + 8) = z;
        *(int4*)(dst + 16) = z; *(int4*)(dst + 24) = z;
      }
    }
  }

  const f32x4 fzero = {0.f, 0.f, 0.f, 0.f};
  f32x4 acc[2][8];
  #pragma unroll
  for (int rg = 0; rg < 2; ++rg)
    #pragma unroll
    for (int i = 0; i < 8; ++i) acc[rg][i] = fzero;

  const int ksub = (tid & 3) * 8;
  const int jb = tid >> 2;

  for (int k0 = 0; k0 < H; k0 += 32) {
    __syncthreads();
    #pragma unroll
    for (int it = 0; it < 8; ++it) {
      int jj = it * 64 + jb;
      const float* src = skip_w + (long)jj * H + k0 + ksub;
      cvt_store8(&Bsl[jj][ksub], *(const float4*)src, *(const float4*)(src + 4));
    }
    __syncthreads();
    bf16x8 af0 = *(const bf16x8*)&Asl[r][k0 + q * 8];
    bf16x8 af1 = *(const bf16x8*)&Asl[16 + r][k0 + q * 8];
    #pragma unroll
    for (int i = 0; i < 8; ++i) {
      bf16x8 bf = *(const bf16x8*)&Bsl[(wv * 8 + i) * 16 + r][q * 8];
      acc[0][i] = __builtin_amdgcn_mfma_f32_16x16x32_bf16(af0, bf, acc[0][i], 0, 0, 0);
      acc[1][i] = __builtin_amdgcn_mfma_f32_16x16x32_bf16(af1, bf, acc[1][i], 0, 0, 0);
    }
  }
  #pragma unroll
  for (int rg = 0; rg < 2; ++rg)
    #pragma unroll
    for (int i = 0; i < 8; ++i) {
      int col = (wv * 8 + i) * 16 + r;
      float sbv = skip_b[col];
      #pragma unroll
      for (int g = 0; g < 4; ++g) {
        int grow = m0 + rg * 16 + q * 4 + g;
        if (grow < NN) out2[(long)grow * H + col] = acc[rg][i][g] + sbv;
      }
    }
}

// ---------------- host launcher (d_ws is UNUSABLE in this harness) ----------
extern "C" void kernel_launch(void* const* d_in, const int* in_sizes, int n_in,
                              void* d_out, int out_size, void* d_ws, size_t ws_size,
                              hipStream_t stream) {
  const float* emb    = (const float*)d_in[0];
  const float* W_ir   = (const float*)d_in[1];
  const float* b_ir   = (const float*)d_in[2];
  const float* W_iz   = (const float*)d_in[3];
  const float* b_iz   = (const float*)d_in[4];
  const float* lin_w  = (const float*)d_in[5];
  const float* lin_b  = (const float*)d_in[6];
  const float* skip_w = (const float*)d_in[7];
  const float* skip_b = (const float*)d_in[8];
  const int*   walk   = (const int*)d_in[9];
  const int*   eli    = (const int*)d_in[10];
  float* out = (float*)d_out;
  float* R   = out + EE;                           // out2 region: NN x H f32
  unsigned short* hnb = (unsigned short*)R;        // bf16 hn inside out2 slots

  dim3 g1(16, 64);
  gru_fused<<<g1, 256, 0, stream>>>(emb, W_ir, W_iz, b_ir, b_iz, walk, hnb);
  score_kernel<<<2500, 256, 0, stream>>>(hnb, lin_w, lin_b, R);
  pred_kernel<<<391, 256, 0, stream>>>(eli, R, out);        // before out2 (slots reused)
  out2_kernel<<<313, 256, 0, stream>>>(hnb, skip_w, skip_b, R);
}

// Round 6
// 727.507 us; speedup vs baseline: 2.9638x; 1.0221x over previous
//
#include <hip/hip_runtime.h>

#define H  512
#define NN 10000
#define SS 20
#define VV 100000
#define EE 100000

typedef __bf16 bf16x8 __attribute__((ext_vector_type(8)));
typedef float  f32x4  __attribute__((ext_vector_type(4)));

__device__ __forceinline__ unsigned short f2bf(float f) {
  unsigned u = __builtin_bit_cast(unsigned, f);
  u += 0x7FFFu + ((u >> 16) & 1u);
  return (unsigned short)(u >> 16);
}
__device__ __forceinline__ float bflo(int x) {
  return __builtin_bit_cast(float, (unsigned)x << 16);
}
__device__ __forceinline__ float bfhi(int x) {
  return __builtin_bit_cast(float, (unsigned)x & 0xFFFF0000u);
}
__device__ __forceinline__ float sigm(float x) { return 1.f / (1.f + __expf(-x)); }

// pack two f32 -> two bf16 in one dword: round-half-up (+0x8000) + v_perm_b32.
__device__ __forceinline__ unsigned pk(float lo, float hi) {
  unsigned a = __builtin_bit_cast(unsigned, lo) + 0x8000u;
  unsigned b = __builtin_bit_cast(unsigned, hi) + 0x8000u;
  return __builtin_amdgcn_perm(b, a, 0x07060302u);
}
__device__ __forceinline__ void cvt_store8(unsigned short* dst, float4 a, float4 b) {
  int4 v;
  v.x = (int)pk(a.x, a.y); v.y = (int)pk(a.z, a.w);
  v.z = (int)pk(b.x, b.y); v.w = (int)pk(b.z, b.w);
  *(int4*)dst = v;
}
__device__ __forceinline__ bf16x8 cvt8(float4 a, float4 b) {
  int4 v;
  v.x = (int)pk(a.x, a.y); v.y = (int)pk(a.z, a.w);
  v.z = (int)pk(b.x, b.y); v.w = (int)pk(b.z, b.w);
  return __builtin_bit_cast(bf16x8, v);
}

// non-draining barrier: publish LDS writes, do NOT drain vmcnt (in-flight
// global loads legally span the barrier). "memory" clobber = compiler fence
// so ds ops can't be moved across it.
__device__ __forceinline__ void pub_barrier() {
  asm volatile("s_waitcnt lgkmcnt(0)\n\ts_barrier" ::: "memory");
}

// ---------------- fused gather + GEMM + GRU scan (persistent-B) -------------
// Geometry = verified 731us config: grid (16 cg x 64 sb), 256 thr = 4 waves,
// wave owns 32 cols (h/z panels of same (layer,channel)), barr = 128 VGPR
// persistent B, acc[5][2], BK=64, 80-row XOR-swizzled A (0 conflicts).
// R4 (700us): 4 LDS buffers, non-draining barrier, store shifted two chunks
// ahead of its reader:
//   body(kc): issue loads(kc+3) ; cvt_store(kc+2) ; ds_read(kc) ; MFMA(kc)
// R5: accounting shows no pipe >45% busy at 2 waves/SIMD; residual ~1400cy of
// the 2692cy slot-pair attributed to 9 barrier rendezvous per ng (~300cy skew
// each: 4 waves on 4 SIMDs, each perturbed by the other block's wave). The
// 4-buffer pipeline tolerates TWO bodies per barrier (stores {kc+2,kc+3} hit
// buffers disjoint from reads {kc,kc+1}; every buffer still has >=1 barrier
// between write->read and read->rewrite, incl. across the ng boundary). So:
// barrier every other kc -> 5 barriers/ng (was 9), and body(kc+1)'s staging
// overlaps body(kc)'s 388cy MFMA burst in one scheduling region.
// XCD swizzle (verified: FETCH 1.33GB->246MB): hwid = by*16+bx;
// sb = (hwid&7)*8 + (hwid>>7), cg = (hwid>>3)&15.
__launch_bounds__(256, 2)
__global__ void gru_fused(const float* __restrict__ emb,
                          const float* __restrict__ W_ir,
                          const float* __restrict__ W_iz,
                          const float* __restrict__ b_ir,
                          const float* __restrict__ b_iz,
                          const int* __restrict__ walk,
                          unsigned short* __restrict__ hnb) {
  __shared__ unsigned short As[4][80 * 64];   // 4 x 10 KB, XOR-swizzled granules
  __shared__ unsigned short hout[2][4][32];   // [ng&1][node][channel-local]

  const int tid = threadIdx.x;
  const int w = tid >> 6, lane = tid & 63;
  const int r = lane & 15, q = lane >> 4;

  // XCD-aware remap (see header comment)
  const int hwid = blockIdx.y * 16 + blockIdx.x;
  const int cg = (hwid >> 3) & 15;
  const int sb = ((hwid & 7) << 3) + (hwid >> 7);
  const int c0 = cg * 32;

  // ---- persistent B fragments: 2 tiles x 16 k-steps x 8 bf16 = 128 VGPRs ---
  const int ly = r & 1;                       // layer of this lane's columns
  const int cch = c0 + 8 * w + (r >> 1);      // channel of this lane's columns
  bf16x8 barr[2][16];
  float bias2[2];
  #pragma unroll
  for (int t = 0; t < 2; ++t) {               // t: 0 = h (W_ir), 1 = z (W_iz)
    const float* wrow = (t ? W_iz : W_ir) + (long)ly * H * H + (long)cch * H;
    #pragma unroll
    for (int u = 0; u < 16; ++u) {
      const float* s = wrow + u * 32 + q * 8;
      barr[t][u] = cvt8(*(const float4*)s, *(const float4*)(s + 4));
    }
    bias2[t] = (t ? b_iz : b_ir)[ly * H + cch];
  }

  // ---- A staging roles: thread -> rows {tid>>3, +32, +64 (if tid<128)} -----
  const int row0 = tid >> 3, g0 = tid & 7;
  const int row1 = row0 + 32, row2 = row0 + 64;
  const bool has2 = (tid < 128);              // wave-uniform (waves 0,1)
  #define LMAP(m) (20 * (((m) >> 2) & 3) + 4 * ((m) >> 4) + ((m) & 3))
  #define SWZ(m)  ((m) * 64 + ((g0 ^ ((m) & 7)) * 8))
  const int L0 = LMAP(row0), L1 = LMAP(row1), L2 = LMAP(row2);
  const int sw0 = SWZ(row0), sw1 = SWZ(row1), sw2 = SWZ(row2);

  const int ngA = (2500 * sb) >> 6;
  const int ngB = (2500 * (sb + 1)) >> 6;

  int v0 = walk[ngA * 80 + L0]; v0 = ((unsigned)v0 < VV) ? v0 : 0;
  int v1 = walk[ngA * 80 + L1]; v1 = ((unsigned)v1 < VV) ? v1 : 0;
  int cur0 = v0 * H, cur1 = v1 * H, cur2 = 0;
  if (has2) { int v2 = walk[ngA * 80 + L2]; v2 = ((unsigned)v2 < VV) ? v2 : 0; cur2 = v2 * H; }

  // pf regs: per row {a,b} float4, 2 parity slots (compile-time indexed)
  float4 p0a[2], p0b[2], p1a[2], p1b[2], p2a[2], p2b[2];
  p2a[0] = p2a[1] = p2b[0] = p2b[1] = (float4){0, 0, 0, 0};

  // ---- prologue: load+store chunks 0,1; issue loads for chunk 2 ------------
  {
    const float* s0 = emb + cur0 + g0 * 8;
    const float* s1 = emb + cur1 + g0 * 8;
    const float* s2 = emb + cur2 + g0 * 8;
    // chunk 0
    float4 a0 = *(const float4*)s0, b0 = *(const float4*)(s0 + 4);
    float4 a1 = *(const float4*)s1, b1 = *(const float4*)(s1 + 4);
    float4 a2 = {0,0,0,0}, b2 = {0,0,0,0};
    if (has2) { a2 = *(const float4*)s2; b2 = *(const float4*)(s2 + 4); }
    cvt_store8(&As[0][sw0], a0, b0);
    cvt_store8(&As[0][sw1], a1, b1);
    if (has2) cvt_store8(&As[0][sw2], a2, b2);
    // chunk 1
    a0 = *(const float4*)(s0 + 64); b0 = *(const float4*)(s0 + 68);
    a1 = *(const float4*)(s1 + 64); b1 = *(const float4*)(s1 + 68);
    if (has2) { a2 = *(const float4*)(s2 + 64); b2 = *(const float4*)(s2 + 68); }
    cvt_store8(&As[1][sw0], a0, b0);
    cvt_store8(&As[1][sw1], a1, b1);
    if (has2) cvt_store8(&As[1][sw2], a2, b2);
    // issue chunk 2 -> parity (2&1)=0
    p0a[0] = *(const float4*)(s0 + 128); p0b[0] = *(const float4*)(s0 + 132);
    p1a[0] = *(const float4*)(s1 + 128); p1b[0] = *(const float4*)(s1 + 132);
    if (has2) { p2a[0] = *(const float4*)(s2 + 128); p2b[0] = *(const float4*)(s2 + 132); }
  }

  f32x4 acc[5][2];
  const f32x4 fz = {0.f, 0.f, 0.f, 0.f};

  for (int ng = ngA; ng < ngB; ++ng) {
    #pragma unroll
    for (int mt = 0; mt < 5; ++mt)
      #pragma unroll
      for (int t = 0; t < 2; ++t) acc[mt][t] = fz;

    const int ngn = (ng + 1 < ngB) ? ng + 1 : ng;   // clamped walk prefetch
    int n0 = walk[ngn * 80 + L0]; n0 = ((unsigned)n0 < VV) ? n0 : 0;
    int n1 = walk[ngn * 80 + L1]; n1 = ((unsigned)n1 < VV) ? n1 : 0;
    const int nxt0 = n0 * H, nxt1 = n1 * H;
    int nxt2 = 0;
    if (has2) { int n2 = walk[ngn * 80 + L2]; n2 = ((unsigned)n2 < VV) ? n2 : 0; nxt2 = n2 * H; }

    #pragma unroll
    for (int kc = 0; kc < 8; ++kc) {
      // (a) barrier every OTHER body: publishes the previous pair's stores,
      // retires the previous pair's reads. 4-buffer pipeline keeps the two
      // bodies between barriers on disjoint buffers (proof in header).
      if ((kc & 1) == 0) pub_barrier();

      // (b) issue loads for chunk kc+3 (wraps into next ng's chunks 0..2)
      {
        const int cix = kc + 3;                     // 3..10, compile-time
        const int off = (cix & 7) * 64;
        const int u0 = (cix < 8) ? cur0 : nxt0;
        const int u1 = (cix < 8) ? cur1 : nxt1;
        const float* s0 = emb + u0 + off + g0 * 8;
        p0a[cix & 1] = *(const float4*)s0; p0b[cix & 1] = *(const float4*)(s0 + 4);
        const float* s1 = emb + u1 + off + g0 * 8;
        p1a[cix & 1] = *(const float4*)s1; p1b[cix & 1] = *(const float4*)(s1 + 4);
        if (has2) {
          const int u2 = (cix < 8) ? cur2 : nxt2;
          const float* s2 = emb + u2 + off + g0 * 8;
          p2a[cix & 1] = *(const float4*)s2; p2b[cix & 1] = *(const float4*)(s2 + 4);
        }
      }

      // (c) cvt+store chunk kc+2 (loads issued last body-pair; auto-vmcnt)
      {
        unsigned short* An = &As[(kc + 2) & 3][0];
        cvt_store8(&An[sw0], p0a[kc & 1], p0b[kc & 1]);   // (kc+2)&1 == kc&1
        cvt_store8(&An[sw1], p1a[kc & 1], p1b[kc & 1]);
        if (has2) cvt_store8(&An[sw2], p2a[kc & 1], p2b[kc & 1]);
      }

      // (d)+(e) frag reads + MFMA for chunk kc (published >=1 barrier ago)
      const unsigned short* Ab = &As[kc & 3][0];
      #pragma unroll
      for (int ks = 0; ks < 2; ++ks) {
        bf16x8 a[5];
        #pragma unroll
        for (int mt = 0; mt < 5; ++mt) {
          const int ar = mt * 16 + r;
          a[mt] = *(const bf16x8*)&Ab[ar * 64 + (((ks * 4 + q) ^ (ar & 7)) * 8)];
        }
        __builtin_amdgcn_s_setprio(1);
        #pragma unroll
        for (int mt = 0; mt < 5; ++mt)
          #pragma unroll
          for (int t = 0; t < 2; ++t)
            acc[mt][t] = __builtin_amdgcn_mfma_f32_16x16x32_bf16(
                a[mt], barr[t][kc * 2 + ks], acc[mt][t], 0, 0, 0);
        __builtin_amdgcn_s_setprio(0);
      }
    }

    // ---- epilogue: pure lane-local scan (h and z live in the same lane) ----
    {
      float hn1 = 0.f, a2 = 1.f, b2 = 0.f;
      #pragma unroll
      for (int s = 0; s < 20; ++s) {
        const float yh = acc[s >> 2][0][s & 3] + bias2[0];
        const float yz = acc[s >> 2][1][s & 3] + bias2[1];
        const float z = sigm(yz);
        hn1 += z * (yh - hn1);     // layer-1 direct scan (valid on ly==0 lanes)
        a2 *= (1.f - z);           // layer-2 affine (valid on ly==1 lanes)
        b2 += z * (yh - b2);
      }
      const float u2 = __shfl_xor(hn1, 1);    // ly1 lane gets ly0's hn1
      if (ly == 1) hout[ng & 1][q][8 * w + (r >> 1)] = f2bf(a2 * u2 + b2);
    }
    // publishes hout AND retires the last body-pair's frag reads before the
    // next ng's first stores rewrite those buffers.
    pub_barrier();
    // packed store: 16 threads write 4 nodes x 64B (4 x dwordx4, same line)
    if (tid < 16) {
      const int nd = tid >> 2, seg = tid & 3;
      int4 v = *(const int4*)&hout[ng & 1][nd][seg * 8];
      *(int4*)(hnb + (long)(ng * 4 + nd) * 1024 + c0 + seg * 8) = v;
    }
    cur0 = nxt0; cur1 = nxt1; cur2 = nxt2;
  }
}

// ------- score slot (raw sigmoid) = sigmoid(hn . lin_w + lin_b) -------------
__global__ void score_kernel(const unsigned short* __restrict__ hnb,
                             const float* __restrict__ lin_w,
                             const float* __restrict__ lin_b,
                             float* __restrict__ R) {
  int tid = threadIdx.x;
  int wv = tid >> 6, lane = tid & 63;
  int node = blockIdx.x * 4 + wv;
  int k = lane * 8;
  int4 hv = *(const int4*)(hnb + (long)node * 1024 + k);
  float4 w0 = *(const float4*)(lin_w + k);
  float4 w1 = *(const float4*)(lin_w + k + 4);
  float s = bflo(hv.x) * w0.x + bfhi(hv.x) * w0.y + bflo(hv.y) * w0.z + bfhi(hv.y) * w0.w
          + bflo(hv.z) * w1.x + bfhi(hv.z) * w1.y + bflo(hv.w) * w1.z + bfhi(hv.w) * w1.w;
  #pragma unroll
  for (int off = 32; off > 0; off >>= 1) s += __shfl_down(s, off);
  if (lane == 0) R[256 + (long)node * 512] = sigm(s + lin_b[0]);
}

// ---------------- pred[e] = score[src] * score[dst] -------------------------
__global__ void pred_kernel(const int* __restrict__ eli, const float* __restrict__ R,
                            float* __restrict__ out) {
  int e = blockIdx.x * 256 + threadIdx.x;
  if (e < EE) {
    int a = eli[e];       a = (unsigned)a < NN ? a : 0;
    int b = eli[EE + e];  b = (unsigned)b < NN ? b : 0;
    out[e] = R[256 + (long)a * 512] * R[256 + (long)b * 512];
  }
}

// ---------------- out2 = hn @ skip_w.T + skip_b (in-place-safe MFMA) --------
__launch_bounds__(256)
__global__ void out2_kernel(const unsigned short* __restrict__ hnb,
                            const float* __restrict__ skip_w,
                            const float* __restrict__ skip_b,
                            float* __restrict__ out2) {
  __shared__ unsigned short Asl[32][520];
  __shared__ unsigned short Bsl[512][40];
  const int tid = threadIdx.x;
  const int lane = tid & 63, wv = tid >> 6;
  const int r = lane & 15, q = lane >> 4;
  const int m0 = blockIdx.x * 32;

  {
    int arow = tid >> 4;
    int acol = (tid & 15) * 32;
    #pragma unroll
    for (int hh = 0; hh < 2; ++hh) {
      int grow = m0 + hh * 16 + arow;
      unsigned short* dst = &Asl[hh * 16 + arow][acol];
      if (grow < NN) {
        const unsigned short* hr = hnb + (long)grow * 1024 + acol;
        *(int4*)(dst)      = *(const int4*)(hr);
        *(int4*)(dst + 8)  = *(const int4*)(hr + 8);
        *(int4*)(dst + 16) = *(const int4*)(hr + 16);
        *(int4*)(dst + 24) = *(const int4*)(hr + 24);
      } else {
        int4 z = {0, 0, 0, 0};
        *(int4*)(dst) = z; *(int4*)(dst + 8) = z;
        *(int4*)(dst + 16) = z; *(int4*)(dst + 24) = z;
      }
    }
  }

  const f32x4 fzero = {0.f, 0.f, 0.f, 0.f};
  f32x4 acc[2][8];
  #pragma unroll
  for (int rg = 0; rg < 2; ++rg)
    #pragma unroll
    for (int i = 0; i < 8; ++i) acc[rg][i] = fzero;

  const int ksub = (tid & 3) * 8;
  const int jb = tid >> 2;

  for (int k0 = 0; k0 < H; k0 += 32) {
    __syncthreads();
    #pragma unroll
    for (int it = 0; it < 8; ++it) {
      int jj = it * 64 + jb;
      const float* src = skip_w + (long)jj * H + k0 + ksub;
      cvt_store8(&Bsl[jj][ksub], *(const float4*)src, *(const float4*)(src + 4));
    }
    __syncthreads();
    bf16x8 af0 = *(const bf16x8*)&Asl[r][k0 + q * 8];
    bf16x8 af1 = *(const bf16x8*)&Asl[16 + r][k0 + q * 8];
    #pragma unroll
    for (int i = 0; i < 8; ++i) {
      bf16x8 bf = *(const bf16x8*)&Bsl[(wv * 8 + i) * 16 + r][q * 8];
      acc[0][i] = __builtin_amdgcn_mfma_f32_16x16x32_bf16(af0, bf, acc[0][i], 0, 0, 0);
      acc[1][i] = __builtin_amdgcn_mfma_f32_16x16x32_bf16(af1, bf, acc[1][i], 0, 0, 0);
    }
  }
  #pragma unroll
  for (int rg = 0; rg < 2; ++rg)
    #pragma unroll
    for (int i = 0; i < 8; ++i) {
      int col = (wv * 8 + i) * 16 + r;
      float sbv = skip_b[col];
      #pragma unroll
      for (int g = 0; g < 4; ++g) {
        int grow = m0 + rg * 16 + q * 4 + g;
        if (grow < NN) out2[(long)grow * H + col] = acc[rg][i][g] + sbv;
      }
    }
}

// ---------------- host launcher (d_ws is UNUSABLE in this harness) ----------
extern "C" void kernel_launch(void* const* d_in, const int* in_sizes, int n_in,
                              void* d_out, int out_size, void* d_ws, size_t ws_size,
                              hipStream_t stream) {
  const float* emb    = (const float*)d_in[0];
  const float* W_ir   = (const float*)d_in[1];
  const float* b_ir   = (const float*)d_in[2];
  const float* W_iz   = (const float*)d_in[3];
  const float* b_iz   = (const float*)d_in[4];
  const float* lin_w  = (const float*)d_in[5];
  const float* lin_b  = (const float*)d_in[6];
  const float* skip_w = (const float*)d_in[7];
  const float* skip_b = (const float*)d_in[8];
  const int*   walk   = (const int*)d_in[9];
  const int*   eli    = (const int*)d_in[10];
  float* out = (float*)d_out;
  float* R   = out + EE;                           // out2 region: NN x H f32
  unsigned short* hnb = (unsigned short*)R;        // bf16 hn inside out2 slots

  dim3 g1(16, 64);
  gru_fused<<<g1, 256, 0, stream>>>(emb, W_ir, W_iz, b_ir, b_iz, walk, hnb);
  score_kernel<<<2500, 256, 0, stream>>>(hnb, lin_w, lin_b, R);
  pred_kernel<<<391, 256, 0, stream>>>(eli, R, out);        // before out2 (slots reused)
  out2_kernel<<<313, 256, 0, stream>>>(hnb, skip_w, skip_b, R);
}

// Round 7
// 680.179 us; speedup vs baseline: 3.1700x; 1.0696x over previous
//
#include <hip/hip_runtime.h>

#define H  512
#define NN 10000
#define SS 20
#define VV 100000
#define EE 100000

typedef __bf16 bf16x8 __attribute__((ext_vector_type(8)));
typedef float  f32x4  __attribute__((ext_vector_type(4)));

__device__ __forceinline__ unsigned short f2bf(float f) {
  unsigned u = __builtin_bit_cast(unsigned, f);
  u += 0x7FFFu + ((u >> 16) & 1u);
  return (unsigned short)(u >> 16);
}
__device__ __forceinline__ float bflo(int x) {
  return __builtin_bit_cast(float, (unsigned)x << 16);
}
__device__ __forceinline__ float bfhi(int x) {
  return __builtin_bit_cast(float, (unsigned)x & 0xFFFF0000u);
}
__device__ __forceinline__ float sigm(float x) { return 1.f / (1.f + __expf(-x)); }

// pack two f32 -> two bf16 in one dword via the HW packed convert (1 VALU op
// vs 3 for the add+perm trick). dst.lo16 = bf16(lo), dst.hi16 = bf16(hi).
__device__ __forceinline__ unsigned cpk(float lo, float hi) {
  unsigned r;
  asm("v_cvt_pk_bf16_f32 %0, %1, %2" : "=v"(r) : "v"(lo), "v"(hi));
  return r;
}
__device__ __forceinline__ void cvt_store8(unsigned short* dst, float4 a, float4 b) {
  int4 v;
  v.x = (int)cpk(a.x, a.y); v.y = (int)cpk(a.z, a.w);
  v.z = (int)cpk(b.x, b.y); v.w = (int)cpk(b.z, b.w);
  *(int4*)dst = v;
}
__device__ __forceinline__ bf16x8 cvt8(float4 a, float4 b) {
  int4 v;
  v.x = (int)cpk(a.x, a.y); v.y = (int)cpk(a.z, a.w);
  v.z = (int)cpk(b.x, b.y); v.w = (int)cpk(b.z, b.w);
  return __builtin_bit_cast(bf16x8, v);
}

// non-draining barrier: publish LDS writes, do NOT drain vmcnt (in-flight
// global loads legally span the barrier). "memory" clobber = compiler fence
// so ds ops can't be moved across it.
__device__ __forceinline__ void pub_barrier() {
  asm volatile("s_waitcnt lgkmcnt(0)\n\ts_barrier" ::: "memory");
}

// ---------------- fused gather + GEMM + GRU scan (persistent-B) -------------
// Geometry = verified 731us config: 256 thr = 4 waves, wave owns 32 cols
// (h/z panels of same (layer,channel)), barr = 128 VGPR persistent B,
// acc[5][2], BK=64, 80-row XOR-swizzled A (0 conflicts).
// R4 (700us): 4 LDS buffers, non-draining barrier, store 2 chunks ahead:
//   body(kc): issue loads(kc+3) ; cvt_store(kc+2) ; ds_read(kc) ; MFMA(kc)
// R5 (678us): barrier every OTHER body (disjoint-buffer proof in r5 notes).
// R6 micro-bundle (occupancy hard-capped at 2 waves/SIMD: barr128+acc40=168
// regs in the unified file -> 3 waves can't fit; structural levers exhausted
// at <=3% each):
//  - drop s_setprio (m190: hurts lockstep symmetric-wave GEMM)
//  - v_cvt_pk_bf16_f32 packing: 1 VALU per 2 floats (was 3) on the ~50%-busy
//    issue port
//  - grid 1024->512 (16cg x 32sb), ONE residency generation: kills one
//    prologue per CU + inter-generation tail; co-resident blocks drift apart.
// XCD swizzle (verified: FETCH 1.33GB->246MB): hwid = by*16+bx, xcd = hwid&7;
// cg = (hwid>>3)&15, sb = (hwid&7)*4 + (hwid>>7)  (bijective: hwid <-> (xcd,
// cg, gen); all 16 cg of an sb on one XCD).
__launch_bounds__(256, 2)
__global__ void gru_fused(const float* __restrict__ emb,
                          const float* __restrict__ W_ir,
                          const float* __restrict__ W_iz,
                          const float* __restrict__ b_ir,
                          const float* __restrict__ b_iz,
                          const int* __restrict__ walk,
                          unsigned short* __restrict__ hnb) {
  __shared__ unsigned short As[4][80 * 64];   // 4 x 10 KB, XOR-swizzled granules
  __shared__ unsigned short hout[2][4][32];   // [ng&1][node][channel-local]

  const int tid = threadIdx.x;
  const int w = tid >> 6, lane = tid & 63;
  const int r = lane & 15, q = lane >> 4;

  // XCD-aware remap (see header comment)
  const int hwid = blockIdx.y * 16 + blockIdx.x;
  const int cg = (hwid >> 3) & 15;
  const int sb = ((hwid & 7) << 2) + (hwid >> 7);
  const int c0 = cg * 32;

  // ---- persistent B fragments: 2 tiles x 16 k-steps x 8 bf16 = 128 VGPRs ---
  const int ly = r & 1;                       // layer of this lane's columns
  const int cch = c0 + 8 * w + (r >> 1);      // channel of this lane's columns
  bf16x8 barr[2][16];
  float bias2[2];
  #pragma unroll
  for (int t = 0; t < 2; ++t) {               // t: 0 = h (W_ir), 1 = z (W_iz)
    const float* wrow = (t ? W_iz : W_ir) + (long)ly * H * H + (long)cch * H;
    #pragma unroll
    for (int u = 0; u < 16; ++u) {
      const float* s = wrow + u * 32 + q * 8;
      barr[t][u] = cvt8(*(const float4*)s, *(const float4*)(s + 4));
    }
    bias2[t] = (t ? b_iz : b_ir)[ly * H + cch];
  }

  // ---- A staging roles: thread -> rows {tid>>3, +32, +64 (if tid<128)} -----
  const int row0 = tid >> 3, g0 = tid & 7;
  const int row1 = row0 + 32, row2 = row0 + 64;
  const bool has2 = (tid < 128);              // wave-uniform (waves 0,1)
  #define LMAP(m) (20 * (((m) >> 2) & 3) + 4 * ((m) >> 4) + ((m) & 3))
  #define SWZ(m)  ((m) * 64 + ((g0 ^ ((m) & 7)) * 8))
  const int L0 = LMAP(row0), L1 = LMAP(row1), L2 = LMAP(row2);
  const int sw0 = SWZ(row0), sw1 = SWZ(row1), sw2 = SWZ(row2);

  const int ngA = (2500 * sb) >> 5;
  const int ngB = (2500 * (sb + 1)) >> 5;

  int v0 = walk[ngA * 80 + L0]; v0 = ((unsigned)v0 < VV) ? v0 : 0;
  int v1 = walk[ngA * 80 + L1]; v1 = ((unsigned)v1 < VV) ? v1 : 0;
  int cur0 = v0 * H, cur1 = v1 * H, cur2 = 0;
  if (has2) { int v2 = walk[ngA * 80 + L2]; v2 = ((unsigned)v2 < VV) ? v2 : 0; cur2 = v2 * H; }

  // pf regs: per row {a,b} float4, 2 parity slots (compile-time indexed)
  float4 p0a[2], p0b[2], p1a[2], p1b[2], p2a[2], p2b[2];
  p2a[0] = p2a[1] = p2b[0] = p2b[1] = (float4){0, 0, 0, 0};

  // ---- prologue: load+store chunks 0,1; issue loads for chunk 2 ------------
  {
    const float* s0 = emb + cur0 + g0 * 8;
    const float* s1 = emb + cur1 + g0 * 8;
    const float* s2 = emb + cur2 + g0 * 8;
    // chunk 0
    float4 a0 = *(const float4*)s0, b0 = *(const float4*)(s0 + 4);
    float4 a1 = *(const float4*)s1, b1 = *(const float4*)(s1 + 4);
    float4 a2 = {0,0,0,0}, b2 = {0,0,0,0};
    if (has2) { a2 = *(const float4*)s2; b2 = *(const float4*)(s2 + 4); }
    cvt_store8(&As[0][sw0], a0, b0);
    cvt_store8(&As[0][sw1], a1, b1);
    if (has2) cvt_store8(&As[0][sw2], a2, b2);
    // chunk 1
    a0 = *(const float4*)(s0 + 64); b0 = *(const float4*)(s0 + 68);
    a1 = *(const float4*)(s1 + 64); b1 = *(const float4*)(s1 + 68);
    if (has2) { a2 = *(const float4*)(s2 + 64); b2 = *(const float4*)(s2 + 68); }
    cvt_store8(&As[1][sw0], a0, b0);
    cvt_store8(&As[1][sw1], a1, b1);
    if (has2) cvt_store8(&As[1][sw2], a2, b2);
    // issue chunk 2 -> parity (2&1)=0
    p0a[0] = *(const float4*)(s0 + 128); p0b[0] = *(const float4*)(s0 + 132);
    p1a[0] = *(const float4*)(s1 + 128); p1b[0] = *(const float4*)(s1 + 132);
    if (has2) { p2a[0] = *(const float4*)(s2 + 128); p2b[0] = *(const float4*)(s2 + 132); }
  }

  f32x4 acc[5][2];
  const f32x4 fz = {0.f, 0.f, 0.f, 0.f};

  for (int ng = ngA; ng < ngB; ++ng) {
    #pragma unroll
    for (int mt = 0; mt < 5; ++mt)
      #pragma unroll
      for (int t = 0; t < 2; ++t) acc[mt][t] = fz;

    const int ngn = (ng + 1 < ngB) ? ng + 1 : ng;   // clamped walk prefetch
    int n0 = walk[ngn * 80 + L0]; n0 = ((unsigned)n0 < VV) ? n0 : 0;
    int n1 = walk[ngn * 80 + L1]; n1 = ((unsigned)n1 < VV) ? n1 : 0;
    const int nxt0 = n0 * H, nxt1 = n1 * H;
    int nxt2 = 0;
    if (has2) { int n2 = walk[ngn * 80 + L2]; n2 = ((unsigned)n2 < VV) ? n2 : 0; nxt2 = n2 * H; }

    #pragma unroll
    for (int kc = 0; kc < 8; ++kc) {
      // (a) barrier every OTHER body: publishes the previous pair's stores,
      // retires the previous pair's reads. 4-buffer pipeline keeps the two
      // bodies between barriers on disjoint buffers.
      if ((kc & 1) == 0) pub_barrier();

      // (b) issue loads for chunk kc+3 (wraps into next ng's chunks 0..2)
      {
        const int cix = kc + 3;                     // 3..10, compile-time
        const int off = (cix & 7) * 64;
        const int u0 = (cix < 8) ? cur0 : nxt0;
        const int u1 = (cix < 8) ? cur1 : nxt1;
        const float* s0 = emb + u0 + off + g0 * 8;
        p0a[cix & 1] = *(const float4*)s0; p0b[cix & 1] = *(const float4*)(s0 + 4);
        const float* s1 = emb + u1 + off + g0 * 8;
        p1a[cix & 1] = *(const float4*)s1; p1b[cix & 1] = *(const float4*)(s1 + 4);
        if (has2) {
          const int u2 = (cix < 8) ? cur2 : nxt2;
          const float* s2 = emb + u2 + off + g0 * 8;
          p2a[cix & 1] = *(const float4*)s2; p2b[cix & 1] = *(const float4*)(s2 + 4);
        }
      }

      // (c) cvt+store chunk kc+2 (loads issued last body-pair; auto-vmcnt)
      {
        unsigned short* An = &As[(kc + 2) & 3][0];
        cvt_store8(&An[sw0], p0a[kc & 1], p0b[kc & 1]);   // (kc+2)&1 == kc&1
        cvt_store8(&An[sw1], p1a[kc & 1], p1b[kc & 1]);
        if (has2) cvt_store8(&An[sw2], p2a[kc & 1], p2b[kc & 1]);
      }

      // (d)+(e) frag reads + MFMA for chunk kc (published >=1 barrier ago)
      const unsigned short* Ab = &As[kc & 3][0];
      #pragma unroll
      for (int ks = 0; ks < 2; ++ks) {
        bf16x8 a[5];
        #pragma unroll
        for (int mt = 0; mt < 5; ++mt) {
          const int ar = mt * 16 + r;
          a[mt] = *(const bf16x8*)&Ab[ar * 64 + (((ks * 4 + q) ^ (ar & 7)) * 8)];
        }
        #pragma unroll
        for (int mt = 0; mt < 5; ++mt)
          #pragma unroll
          for (int t = 0; t < 2; ++t)
            acc[mt][t] = __builtin_amdgcn_mfma_f32_16x16x32_bf16(
                a[mt], barr[t][kc * 2 + ks], acc[mt][t], 0, 0, 0);
      }
    }

    // ---- epilogue: pure lane-local scan (h and z live in the same lane) ----
    {
      float hn1 = 0.f, a2 = 1.f, b2 = 0.f;
      #pragma unroll
      for (int s = 0; s < 20; ++s) {
        const float yh = acc[s >> 2][0][s & 3] + bias2[0];
        const float yz = acc[s >> 2][1][s & 3] + bias2[1];
        const float z = sigm(yz);
        hn1 += z * (yh - hn1);     // layer-1 direct scan (valid on ly==0 lanes)
        a2 *= (1.f - z);           // layer-2 affine (valid on ly==1 lanes)
        b2 += z * (yh - b2);
      }
      const float u2 = __shfl_xor(hn1, 1);    // ly1 lane gets ly0's hn1
      if (ly == 1) hout[ng & 1][q][8 * w + (r >> 1)] = f2bf(a2 * u2 + b2);
    }
    // publishes hout AND retires the last body-pair's frag reads before the
    // next ng's first stores rewrite those buffers.
    pub_barrier();
    // packed store: 16 threads write 4 nodes x 64B (4 x dwordx4, same line)
    if (tid < 16) {
      const int nd = tid >> 2, seg = tid & 3;
      int4 v = *(const int4*)&hout[ng & 1][nd][seg * 8];
      *(int4*)(hnb + (long)(ng * 4 + nd) * 1024 + c0 + seg * 8) = v;
    }
    cur0 = nxt0; cur1 = nxt1; cur2 = nxt2;
  }
}

// ------- score slot (raw sigmoid) = sigmoid(hn . lin_w + lin_b) -------------
__global__ void score_kernel(const unsigned short* __restrict__ hnb,
                             const float* __restrict__ lin_w,
                             const float* __restrict__ lin_b,
                             float* __restrict__ R) {
  int tid = threadIdx.x;
  int wv = tid >> 6, lane = tid & 63;
  int node = blockIdx.x * 4 + wv;
  int k = lane * 8;
  int4 hv = *(const int4*)(hnb + (long)node * 1024 + k);
  float4 w0 = *(const float4*)(lin_w + k);
  float4 w1 = *(const float4*)(lin_w + k + 4);
  float s = bflo(hv.x) * w0.x + bfhi(hv.x) * w0.y + bflo(hv.y) * w0.z + bfhi(hv.y) * w0.w
          + bflo(hv.z) * w1.x + bfhi(hv.z) * w1.y + bflo(hv.w) * w1.z + bfhi(hv.w) * w1.w;
  #pragma unroll
  for (int off = 32; off > 0; off >>= 1) s += __shfl_down(s, off);
  if (lane == 0) R[256 + (long)node * 512] = sigm(s + lin_b[0]);
}

// ---------------- pred[e] = score[src] * score[dst] -------------------------
__global__ void pred_kernel(const int* __restrict__ eli, const float* __restrict__ R,
                            float* __restrict__ out) {
  int e = blockIdx.x * 256 + threadIdx.x;
  if (e < EE) {
    int a = eli[e];       a = (unsigned)a < NN ? a : 0;
    int b = eli[EE + e];  b = (unsigned)b < NN ? b : 0;
    out[e] = R[256 + (long)a * 512] * R[256 + (long)b * 512];
  }
}

// ---------------- out2 = hn @ skip_w.T + skip_b (in-place-safe MFMA) --------
__launch_bounds__(256)
__global__ void out2_kernel(const unsigned short* __restrict__ hnb,
                            const float* __restrict__ skip_w,
                            const float* __restrict__ skip_b,
                            float* __restrict__ out2) {
  __shared__ unsigned short Asl[32][520];
  __shared__ unsigned short Bsl[512][40];
  const int tid = threadIdx.x;
  const int lane = tid & 63, wv = tid >> 6;
  const int r = lane & 15, q = lane >> 4;
  const int m0 = blockIdx.x * 32;

  {
    int arow = tid >> 4;
    int acol = (tid & 15) * 32;
    #pragma unroll
    for (int hh = 0; hh < 2; ++hh) {
      int grow = m0 + hh * 16 + arow;
      unsigned short* dst = &Asl[hh * 16 + arow][acol];
      if (grow < NN) {
        const unsigned short* hr = hnb + (long)grow * 1024 + acol;
        *(int4*)(dst)      = *(const int4*)(hr);
        *(int4*)(dst + 8)  = *(const int4*)(hr + 8);
        *(int4*)(dst + 16) = *(const int4*)(hr + 16);
        *(int4*)(dst + 24) = *(const int4*)(hr + 24);
      } else {
        int4 z = {0, 0, 0, 0};
        *(int4*)(dst) = z; *(int4*)(dst + 8) = z;
        *(int4*)(dst + 16) = z; *(int4*)(dst + 24) = z;
      }
    }
  }

  const f32x4 fzero = {0.f, 0.f, 0.f, 0.f};
  f32x4 acc[2][8];
  #pragma unroll
  for (int rg = 0; rg < 2; ++rg)
    #pragma unroll
    for (int i = 0; i < 8; ++i) acc[rg][i] = fzero;

  const int ksub = (tid & 3) * 8;
  const int jb = tid >> 2;

  for (int k0 = 0; k0 < H; k0 += 32) {
    __syncthreads();
    #pragma unroll
    for (int it = 0; it < 8; ++it) {
      int jj = it * 64 + jb;
      const float* src = skip_w + (long)jj * H + k0 + ksub;
      cvt_store8(&Bsl[jj][ksub], *(const float4*)src, *(const float4*)(src + 4));
    }
    __syncthreads();
    bf16x8 af0 = *(const bf16x8*)&Asl[r][k0 + q * 8];
    bf16x8 af1 = *(const bf16x8*)&Asl[16 + r][k0 + q * 8];
    #pragma unroll
    for (int i = 0; i < 8; ++i) {
      bf16x8 bf = *(const bf16x8*)&Bsl[(wv * 8 + i) * 16 + r][q * 8];
      acc[0][i] = __builtin_amdgcn_mfma_f32_16x16x32_bf16(af0, bf, acc[0][i], 0, 0, 0);
      acc[1][i] = __builtin_amdgcn_mfma_f32_16x16x32_bf16(af1, bf, acc[1][i], 0, 0, 0);
    }
  }
  #pragma unroll
  for (int rg = 0; rg < 2; ++rg)
    #pragma unroll
    for (int i = 0; i < 8; ++i) {
      int col = (wv * 8 + i) * 16 + r;
      float sbv = skip_b[col];
      #pragma unroll
      for (int g = 0; g < 4; ++g) {
        int grow = m0 + rg * 16 + q * 4 + g;
        if (grow < NN) out2[(long)grow * H + col] = acc[rg][i][g] + sbv;
      }
    }
}

// ---------------- host launcher (d_ws is UNUSABLE in this harness) ----------
extern "C" void kernel_launch(void* const* d_in, const int* in_sizes, int n_in,
                              void* d_out, int out_size, void* d_ws, size_t ws_size,
                              hipStream_t stream) {
  const float* emb    = (const float*)d_in[0];
  const float* W_ir   = (const float*)d_in[1];
  const float* b_ir   = (const float*)d_in[2];
  const float* W_iz   = (const float*)d_in[3];
  const float* b_iz   = (const float*)d_in[4];
  const float* lin_w  = (const float*)d_in[5];
  const float* lin_b  = (const float*)d_in[6];
  const float* skip_w = (const float*)d_in[7];
  const float* skip_b = (const float*)d_in[8];
  const int*   walk   = (const int*)d_in[9];
  const int*   eli    = (const int*)d_in[10];
  float* out = (float*)d_out;
  float* R   = out + EE;                           // out2 region: NN x H f32
  unsigned short* hnb = (unsigned short*)R;        // bf16 hn inside out2 slots

  dim3 g1(16, 32);
  gru_fused<<<g1, 256, 0, stream>>>(emb, W_ir, W_iz, b_ir, b_iz, walk, hnb);
  score_kernel<<<2500, 256, 0, stream>>>(hnb, lin_w, lin_b, R);
  pred_kernel<<<391, 256, 0, stream>>>(eli, R, out);        // before out2 (slots reused)
  out2_kernel<<<313, 256, 0, stream>>>(hnb, skip_w, skip_b, R);
}